// Round 6
// baseline (5808.317 us; speedup 1.0000x reference)
//
#include <hip/hip_runtime.h>
#include <cstdint>
#include <cstddef>

// Model dims
#define T_ 256
#define B_ 128
#define D_ 128
#define H_ 1024
#define K1_ 1152   // D + H
#define K2_ 2048   // 2H

// h1 ring: 32 write-once-per-window slots; agent-acquire fence every R_ steps
#define R_ 32

typedef __bf16 bf16x8 __attribute__((ext_vector_type(8)));
typedef short s8 __attribute__((ext_vector_type(8)));
typedef float f32x4 __attribute__((ext_vector_type(4)));
typedef int i32x4 __attribute__((ext_vector_type(4)));

__device__ __forceinline__ unsigned short f2bf(float f) {
  unsigned int u = __builtin_bit_cast(unsigned int, f);
  u += 0x7fff + ((u >> 16) & 1);   // RNE
  return (unsigned short)(u >> 16);
}
__device__ __forceinline__ float sigm(float x) { return 1.f / (1.f + __expf(-x)); }
__device__ __forceinline__ float tanh_(float x) { return 1.f - 2.f / (__expf(2.f * x) + 1.f); }

__device__ __forceinline__ f32x4 mfma16(s8 a, s8 b, f32x4 c) {
  return __builtin_amdgcn_mfma_f32_16x16x32_bf16(
      __builtin_bit_cast(bf16x8, a), __builtin_bit_cast(bf16x8, b), c, 0, 0, 0);
}

// Write-through 2B store to the coherence point (L3): producers publish h.
__device__ __forceinline__ void st_bypass_short(unsigned short* p, unsigned int v) {
  asm volatile("global_store_short %0, %1, off sc0 sc1" :: "v"(p), "v"(v) : "memory");
}
// Single-writer flag publish (plain dword, write-through).
__device__ __forceinline__ void st_flag(int* p, int v) {
  asm volatile("global_store_dword %0, %1, off sc0 sc1" :: "v"(p), "v"(v) : "memory");
}

// ---------------------------------------------------------------------------
// Prep: convert inSeq -> bf16, pack outW -> [col][k] bf16, zero states/loss,
// zero flags, zero ring slot R_-1 (h1(t=-1)).
// ---------------------------------------------------------------------------
__global__ void prep_misc(const float* __restrict__ inSeq,
                          const float* __restrict__ outW,
                          unsigned short* __restrict__ xbf,
                          unsigned short* __restrict__ outWp,
                          unsigned short* __restrict__ h1b,
                          unsigned short* __restrict__ h1r,
                          unsigned short* __restrict__ h2all,
                          float* __restrict__ c1, float* __restrict__ c2,
                          float* __restrict__ loss,
                          int* __restrict__ f1, int* __restrict__ f2)
{
  int i = blockIdx.x * 256 + threadIdx.x;
  if (i < T_ * B_ * D_) xbf[i] = f2bf(inSeq[i]);
  if (i < B_ * H_) {
    c1[i] = 0.f; c2[i] = 0.f;
    h1b[B_ * H_ + i] = 0;                       // fallback parity-1 buffer
    if (h1r) h1r[(size_t)(R_ - 1) * B_ * H_ + i] = 0;  // ring slot for h1(-1)
    h2all[i] = 0;                               // slot 0 = h2(t=-1)
  }
  if (i < H_ * D_) {          // outWp[c][k] = outW[k][c]
    int c = i >> 10, k = i & 1023;
    outWp[i] = f2bf(outW[(size_t)k * D_ + c]);
  }
  if (f1 && i < 256) { f1[i] = 0; f2[i] = 0; }
  if (i == 0) loss[0] = 0.f;
}

// ---------------------------------------------------------------------------
// Pack LSTM weights: src fp32 [K][4096] (gate-major cols: i|j|f|o blocks of H)
//   -> dst bf16 [4096][K], dst row = 4*j + g  (gate-interleaved, k-major)
// ---------------------------------------------------------------------------
__global__ void pack_w(const float* __restrict__ src, unsigned short* __restrict__ dst, int K)
{
  __shared__ float tile[64][65];
  int k0 = blockIdx.x * 64, j0 = blockIdx.y * 64, g = blockIdx.z;
  int tid = threadIdx.x;
#pragma unroll
  for (int e = 0; e < 16; ++e) {
    int li = e * 256 + tid;
    int kl = li >> 6, jl = li & 63;
    tile[kl][jl] = src[(size_t)(k0 + kl) * 4096 + g * 1024 + j0 + jl];
  }
  __syncthreads();
#pragma unroll
  for (int e = 0; e < 16; ++e) {
    int li = e * 256 + tid;
    int jl = li >> 6, kl = li & 63;
    dst[(size_t)((j0 + jl) * 4 + g) * K + k0 + kl] = f2bf(tile[kl][jl]);
  }
}

// ---------------------------------------------------------------------------
// FALLBACK path (identical to verified kernel): per-phase launches.
// ---------------------------------------------------------------------------
__global__ __launch_bounds__(256, 2) void phase_kernel(
    int p,
    const unsigned short* __restrict__ xbf,
    const unsigned short* __restrict__ W1p,
    const unsigned short* __restrict__ W2p,
    const float* __restrict__ b1,
    const float* __restrict__ b2,
    unsigned short* __restrict__ h1b,
    unsigned short* __restrict__ h2all,
    float* __restrict__ c1,
    float* __restrict__ c2)
{
  __shared__ float red[4][2048];
  const int bid = blockIdx.x;
  const bool isL2 = bid >= 256;
  if (!isL2 && p >= T_) return;
  if (isL2 && p == 0) return;
  const int jb = isL2 ? (bid - 256) : bid;
  const int mt = jb & 1, nt = jb >> 1;
  const int t = isL2 ? (p - 1) : p;
  const int r0 = mt * 64, c0 = nt * 32;
  const int tid = threadIdx.x;
  const int wid = tid >> 6, lane = tid & 63;
  const int quad = lane >> 4, l15 = lane & 15;
  const int kseg = quad * 8;

  const unsigned short* hsrc = h1b + (size_t)((p + 1) & 1) * (B_ * H_);

  f32x4 acc[4][2];
#pragma unroll
  for (int i = 0; i < 4; ++i)
#pragma unroll
    for (int j = 0; j < 2; ++j) acc[i][j] = (f32x4){0.f, 0.f, 0.f, 0.f};

  int arow[4], bcol[2];
#pragma unroll
  for (int i = 0; i < 4; ++i) arow[i] = r0 + i * 16 + l15;
#pragma unroll
  for (int j = 0; j < 2; ++j) bcol[j] = c0 + j * 16 + l15;

  if (!isL2) {
    const unsigned short* xt = xbf + (size_t)t * (B_ * D_);
    const int cpw = 9;
    const int kcbase = wid * cpw;
    s8 a[4], b[2], an[4], bn[2];
    auto LD = [&](int kc, s8* A, s8* Bv) {
      int kk = kc * 32 + kseg;
      if (kk < D_) {
#pragma unroll
        for (int i = 0; i < 4; ++i) A[i] = *(const s8*)(xt + (size_t)arow[i] * D_ + kk);
      } else {
#pragma unroll
        for (int i = 0; i < 4; ++i) A[i] = *(const s8*)(hsrc + (size_t)arow[i] * H_ + (kk - D_));
      }
#pragma unroll
      for (int j = 0; j < 2; ++j) Bv[j] = *(const s8*)(W1p + (size_t)bcol[j] * K1_ + kk);
    };
    LD(kcbase, a, b);
    for (int c = 0; c < cpw; ++c) {
      if (c + 1 < cpw) LD(kcbase + c + 1, an, bn);
#pragma unroll
      for (int i = 0; i < 4; ++i)
#pragma unroll
        for (int j = 0; j < 2; ++j) acc[i][j] = mfma16(a[i], b[j], acc[i][j]);
#pragma unroll
      for (int i = 0; i < 4; ++i) a[i] = an[i];
      b[0] = bn[0]; b[1] = bn[1];
    }
  } else {
    const unsigned short* h2prev = h2all + (size_t)t * (B_ * H_);
    const int cpw = 16;
    const int kcbase = wid * cpw;
    s8 a[4], b[2], an[4], bn[2];
    auto LD = [&](int kc, s8* A, s8* Bv) {
      int kk = kc * 32 + kseg;
      if (kk < H_) {
#pragma unroll
        for (int i = 0; i < 4; ++i) A[i] = *(const s8*)(hsrc + (size_t)arow[i] * H_ + kk);
      } else {
#pragma unroll
        for (int i = 0; i < 4; ++i) A[i] = *(const s8*)(h2prev + (size_t)arow[i] * H_ + (kk - H_));
      }
#pragma unroll
      for (int j = 0; j < 2; ++j) Bv[j] = *(const s8*)(W2p + (size_t)bcol[j] * K2_ + kk);
    };
    LD(kcbase, a, b);
    for (int c = 0; c < cpw; ++c) {
      if (c + 1 < cpw) LD(kcbase + c + 1, an, bn);
#pragma unroll
      for (int i = 0; i < 4; ++i)
#pragma unroll
        for (int j = 0; j < 2; ++j) acc[i][j] = mfma16(a[i], b[j], acc[i][j]);
#pragma unroll
      for (int i = 0; i < 4; ++i) a[i] = an[i];
      b[0] = bn[0]; b[1] = bn[1];
    }
  }

#pragma unroll
  for (int i = 0; i < 4; ++i)
#pragma unroll
    for (int j = 0; j < 2; ++j)
#pragma unroll
      for (int r = 0; r < 4; ++r)
        red[wid][(i * 16 + quad * 4 + r) * 32 + (j * 16 + l15)] = acc[i][j][r];
  __syncthreads();
#pragma unroll
  for (int it = 0; it < 8; ++it) {
    int e = it * 256 + tid;
    red[0][e] = red[0][e] + red[1][e] + red[2][e] + red[3][e];
  }
  __syncthreads();

  const float* bias = isL2 ? b2 : b1;
  float* cst = isL2 ? c2 : c1;
  unsigned short* hout = isL2 ? (h2all + (size_t)(t + 1) * (B_ * H_))
                              : (h1b + (size_t)(p & 1) * (B_ * H_));
#pragma unroll
  for (int it = 0; it < 2; ++it) {
    int s = it * 256 + tid;
    int row = s >> 3, u = s & 7;
    int jg = (c0 >> 2) + u;
    float zi = red[0][row * 32 + u * 4 + 0] + bias[0 * H_ + jg];
    float zj = red[0][row * 32 + u * 4 + 1] + bias[1 * H_ + jg];
    float zf = red[0][row * 32 + u * 4 + 2] + bias[2 * H_ + jg];
    float zo = red[0][row * 32 + u * 4 + 3] + bias[3 * H_ + jg];
    int rg = r0 + row;
    float co = cst[(size_t)rg * H_ + jg];
    float cn = co * sigm(zf + 1.0f) + sigm(zi) * tanh_(zj);
    float hn = tanh_(cn) * sigm(zo);
    cst[(size_t)rg * H_ + jg] = cn;
    hout[(size_t)rg * H_ + jg] = f2bf(hn);
  }
}

// ---------------------------------------------------------------------------
// PERSISTENT kernel: selective per-wave producer waits + depth-3 prefetch.
//  - flags: f1[2*nt+mt] / f2[2*nt+mt] = step count published by that block.
//  - each consumer WAVE waits only on the producer blocks feeding its K-slice
//    (lane l watches one flag). Ring-WAR guards are slack-31 whole-array
//    checks (dwordx4/lane), never on the critical path.
//      L1 wave w: f1 subset (h1(t-1) units it reads) >= t;
//                 all f1 >= t-31 (h1-ring WAR); all f2 >= t-31 (ring WAR)
//      L2 waves 0-1: f1 subset >= t+1 (h1(t));  waves 2-3: f2 subset >= t
//  - data via write-through sc0/sc1 stores + plain cached loads, per-wave
//    agent-acquire fence every R_=32 steps (write-once address windows).
//  - inner loop: 3-buffer rotating chunk prefetch (2 in flight), same MFMA
//    order as verified kernel -> bitwise-identical numerics.
// ---------------------------------------------------------------------------
__global__ __launch_bounds__(256, 2) void lstm_persistent(
    const unsigned short* __restrict__ xbf,
    const unsigned short* __restrict__ W1p,
    const unsigned short* __restrict__ W2p,
    const float* __restrict__ b1,
    const float* __restrict__ b2,
    unsigned short* __restrict__ h1r,
    unsigned short* __restrict__ h2all,
    int* __restrict__ f1,
    int* __restrict__ f2)
{
  __shared__ float red[4][2048];
  const int bid = blockIdx.x;
  const bool isL2 = bid >= 256;
  const int jb = isL2 ? (bid - 256) : bid;
  const int mt = jb & 1, nt = jb >> 1;
  const int r0 = mt * 64, c0 = nt * 32;
  const int tid = threadIdx.x;
  const int wid = tid >> 6, lane = tid & 63;
  const int quad = lane >> 4, l15 = lane & 15;
  const int kseg = quad * 8;
  const int lane4 = lane * 4;

  int arow[4], bcol[2];
#pragma unroll
  for (int i = 0; i < 4; ++i) arow[i] = r0 + i * 16 + l15;
#pragma unroll
  for (int j = 0; j < 2; ++j) bcol[j] = c0 + j * 16 + l15;

  // Register-resident epilogue state (fixed (row,unit) per thread).
  const float* bias = isL2 ? b2 : b1;
  int ridx[2];
  unsigned hoff[2];
  float bz[2][4], creg[2];
#pragma unroll
  for (int it = 0; it < 2; ++it) {
    int s = it * 256 + tid;
    int row = s >> 3, u = s & 7;
    int jg = (c0 >> 2) + u;
    ridx[it] = row * 32 + u * 4;
    hoff[it] = (unsigned)((r0 + row) * H_ + jg);
#pragma unroll
    for (int g = 0; g < 4; ++g) bz[it][g] = bias[g * H_ + jg];
    creg[it] = 0.f;
  }

  if (!isL2) {
    // ----- layer-1 role: K = 1152, 9 chunks/wave -----
    const int kcbase = wid * 9;
    s8 bw[9][2];
#pragma unroll
    for (int c = 0; c < 9; ++c) {
      int kk = (kcbase + c) * 32 + kseg;
      bw[c][0] = *(const s8*)(W1p + (size_t)bcol[0] * K1_ + kk);
      bw[c][1] = *(const s8*)(W1p + (size_t)bcol[1] * K1_ + kk);
    }
#pragma unroll
    for (int c = 0; c < 9; ++c)
      asm volatile("" : "+v"(bw[c][0]), "+v"(bw[c][1]));   // pin in regs

    // selective producer subset: h1 units this wave reads -> L1 blocks
    // wid0: nt 0..19 (n=20); wid1: 20..55; wid2: 56..91; wid3: 92..127
    const int sbase = wid ? (20 + 36 * (wid - 1)) : 0;
    const int sn = wid ? 36 : 20;
    const int* sf = f1 + (2 * (sbase + (lane < sn ? lane : 0)) + mt);
    const int* g1 = f1 + lane4;
    const int* g2 = f2 + lane4;

    for (int t = 0; t < T_; ++t) {
      const int wg = t - (R_ - 1);
      for (;;) {
        int v; i32x4 w1, w2;
        asm volatile("global_load_dword %0, %3, off sc0 sc1\n\t"
                     "global_load_dwordx4 %1, %4, off sc0 sc1\n\t"
                     "global_load_dwordx4 %2, %5, off sc0 sc1\n\t"
                     "s_waitcnt vmcnt(0)"
                     : "=v"(v), "=v"(w1), "=v"(w2)
                     : "v"(sf), "v"(g1), "v"(g2) : "memory");
        int ok = ((lane >= sn) || (v >= t)) &&
                 (w1.x >= wg) && (w1.y >= wg) && (w1.z >= wg) && (w1.w >= wg) &&
                 (w2.x >= wg) && (w2.y >= wg) && (w2.z >= wg) && (w2.w >= wg);
        if (__all(ok)) break;
      }
      if ((t & (R_ - 1)) == 0 && t)
        __builtin_amdgcn_fence(__ATOMIC_ACQUIRE, "agent"); // flush >=R_-old lines

      const unsigned short* hsrc = h1r + (size_t)((t + R_ - 1) & (R_ - 1)) * (B_ * H_);
      const unsigned short* xt = xbf + (size_t)t * (B_ * D_);
      f32x4 acc[4][2];
#pragma unroll
      for (int i = 0; i < 4; ++i)
#pragma unroll
        for (int j = 0; j < 2; ++j) acc[i][j] = (f32x4){0.f, 0.f, 0.f, 0.f};
      s8 ab[3][4];
      auto LD = [&](int kc, s8* A) {
        int kk = kc * 32 + kseg;
        if (kk < D_) {
#pragma unroll
          for (int i = 0; i < 4; ++i) A[i] = *(const s8*)(xt + (size_t)arow[i] * D_ + kk);
        } else {
#pragma unroll
          for (int i = 0; i < 4; ++i) A[i] = *(const s8*)(hsrc + (size_t)arow[i] * H_ + (kk - D_));
        }
      };
      LD(kcbase + 0, ab[0]);
      LD(kcbase + 1, ab[1]);
#pragma unroll
      for (int c = 0; c < 9; ++c) {
        if (c + 2 < 9) LD(kcbase + c + 2, ab[(c + 2) % 3]);
#pragma unroll
        for (int i = 0; i < 4; ++i)
#pragma unroll
          for (int j = 0; j < 2; ++j) acc[i][j] = mfma16(ab[c % 3][i], bw[c][j], acc[i][j]);
      }
#pragma unroll
      for (int i = 0; i < 4; ++i)
#pragma unroll
        for (int j = 0; j < 2; ++j)
#pragma unroll
          for (int r = 0; r < 4; ++r)
            red[wid][(i * 16 + quad * 4 + r) * 32 + (j * 16 + l15)] = acc[i][j][r];
      __syncthreads();
#pragma unroll
      for (int it = 0; it < 8; ++it) {
        int e = it * 256 + tid;
        red[0][e] = red[0][e] + red[1][e] + red[2][e] + red[3][e];
      }
      __syncthreads();
      unsigned short* hout = h1r + (size_t)(t & (R_ - 1)) * (B_ * H_);
#pragma unroll
      for (int it = 0; it < 2; ++it) {
        float zi = red[0][ridx[it] + 0] + bz[it][0];
        float zj = red[0][ridx[it] + 1] + bz[it][1];
        float zf = red[0][ridx[it] + 2] + bz[it][2];
        float zo = red[0][ridx[it] + 3] + bz[it][3];
        float cn = creg[it] * sigm(zf + 1.0f) + sigm(zi) * tanh_(zj);
        float hn = tanh_(cn) * sigm(zo);
        creg[it] = cn;
        st_bypass_short(hout + hoff[it], (unsigned int)f2bf(hn));
      }
      asm volatile("s_waitcnt vmcnt(0)" ::: "memory");  // h1(t) at L3
      __syncthreads();                                  // all threads drained
      if (tid == 0) st_flag(f1 + jb, t + 1);            // single-writer publish
    }
  } else {
    // ----- layer-2 role: K = 2048, 16 chunks/wave -----
    const int kcbase = wid * 16;
    s8 bw[16][2];
#pragma unroll
    for (int c = 0; c < 16; ++c) {
      int kk = (kcbase + c) * 32 + kseg;
      bw[c][0] = *(const s8*)(W2p + (size_t)bcol[0] * K2_ + kk);
      bw[c][1] = *(const s8*)(W2p + (size_t)bcol[1] * K2_ + kk);
    }
#pragma unroll
    for (int c = 0; c < 16; ++c)
      asm volatile("" : "+v"(bw[c][0]), "+v"(bw[c][1]));   // pin in regs

    // selective producer subset: waves 0-1 read h1(t) units wid*512..+511
    // (L1 blocks nt=64*wid..+63); waves 2-3 read h2(t-1) units (wid-2)*512..
    const int* sf = (wid < 2)
        ? (f1 + (2 * (64 * wid + lane) + mt))
        : (f2 + (2 * (64 * (wid - 2) + lane) + mt));

    for (int t = 0; t < T_; ++t) {
      const int want = (wid < 2) ? (t + 1) : t;
      for (;;) {
        int v;
        asm volatile("global_load_dword %0, %1, off sc0 sc1\n\t"
                     "s_waitcnt vmcnt(0)"
                     : "=v"(v) : "v"(sf) : "memory");
        if (__all(v >= want)) break;
      }
      if ((t & (R_ - 1)) == 0 && t)
        __builtin_amdgcn_fence(__ATOMIC_ACQUIRE, "agent");

      const unsigned short* hsrc = h1r + (size_t)(t & (R_ - 1)) * (B_ * H_);
      const unsigned short* h2prev = h2all + (size_t)t * (B_ * H_);
      f32x4 acc[4][2];
#pragma unroll
      for (int i = 0; i < 4; ++i)
#pragma unroll
        for (int j = 0; j < 2; ++j) acc[i][j] = (f32x4){0.f, 0.f, 0.f, 0.f};
      s8 ab[3][4];
      auto LD = [&](int kc, s8* A) {
        int kk = kc * 32 + kseg;
        if (kk < H_) {
#pragma unroll
          for (int i = 0; i < 4; ++i) A[i] = *(const s8*)(hsrc + (size_t)arow[i] * H_ + kk);
        } else {
#pragma unroll
          for (int i = 0; i < 4; ++i) A[i] = *(const s8*)(h2prev + (size_t)arow[i] * H_ + (kk - H_));
        }
      };
      LD(kcbase + 0, ab[0]);
      LD(kcbase + 1, ab[1]);
#pragma unroll
      for (int c = 0; c < 16; ++c) {
        if (c + 2 < 16) LD(kcbase + c + 2, ab[(c + 2) % 3]);
#pragma unroll
        for (int i = 0; i < 4; ++i)
#pragma unroll
          for (int j = 0; j < 2; ++j) acc[i][j] = mfma16(ab[c % 3][i], bw[c][j], acc[i][j]);
      }
#pragma unroll
      for (int i = 0; i < 4; ++i)
#pragma unroll
        for (int j = 0; j < 2; ++j)
#pragma unroll
          for (int r = 0; r < 4; ++r)
            red[wid][(i * 16 + quad * 4 + r) * 32 + (j * 16 + l15)] = acc[i][j][r];
      __syncthreads();
#pragma unroll
      for (int it = 0; it < 8; ++it) {
        int e = it * 256 + tid;
        red[0][e] = red[0][e] + red[1][e] + red[2][e] + red[3][e];
      }
      __syncthreads();
      unsigned short* hout = h2all + (size_t)(t + 1) * (B_ * H_);
#pragma unroll
      for (int it = 0; it < 2; ++it) {
        float zi = red[0][ridx[it] + 0] + bz[it][0];
        float zj = red[0][ridx[it] + 1] + bz[it][1];
        float zf = red[0][ridx[it] + 2] + bz[it][2];
        float zo = red[0][ridx[it] + 3] + bz[it][3];
        float cn = creg[it] * sigm(zf + 1.0f) + sigm(zi) * tanh_(zj);
        float hn = tanh_(cn) * sigm(zo);
        creg[it] = cn;
        st_bypass_short(hout + hoff[it], (unsigned int)f2bf(hn));
      }
      asm volatile("s_waitcnt vmcnt(0)" ::: "memory");
      __syncthreads();
      if (tid == 0) st_flag(f2 + jb, t + 1);            // single-writer publish
    }
  }
}

// ---------------------------------------------------------------------------
// Tail: logits = h2 @ outW + outB, dual softmax, probs out, CE loss.
// ---------------------------------------------------------------------------
__global__ __launch_bounds__(256, 1) void proj_kernel(
    const unsigned short* __restrict__ h2flat,
    const unsigned short* __restrict__ outWp,
    const float* __restrict__ outB,
    const int* __restrict__ targets,
    float* __restrict__ out,
    float* __restrict__ loss)
{
  __shared__ float lg[128][129];
  __shared__ float red2[256];
  const int r0 = blockIdx.x * 128;
  const int tid = threadIdx.x;
  const int wid = tid >> 6, lane = tid & 63;
  const int quad = lane >> 4, l15 = lane & 15;
  const int wr = (wid & 1) * 64, wc = (wid >> 1) * 64;
  const int kseg = quad * 8;

  f32x4 acc[4][4];
#pragma unroll
  for (int i = 0; i < 4; ++i)
#pragma unroll
    for (int j = 0; j < 4; ++j) acc[i][j] = (f32x4){0.f, 0.f, 0.f, 0.f};

  int arow[4], bcolv[4];
#pragma unroll
  for (int i = 0; i < 4; ++i) arow[i] = r0 + wr + i * 16 + l15;
#pragma unroll
  for (int j = 0; j < 4; ++j) bcolv[j] = wc + j * 16 + l15;

  s8 a[4], b[4], an[4], bn[4];
  auto LD = [&](int kc, s8* A, s8* Bv) {
    int kk = kc * 32 + kseg;
#pragma unroll
    for (int i = 0; i < 4; ++i) A[i] = *(const s8*)(h2flat + (size_t)arow[i] * H_ + kk);
#pragma unroll
    for (int j = 0; j < 4; ++j) Bv[j] = *(const s8*)(outWp + (size_t)bcolv[j] * H_ + kk);
  };
  LD(0, a, b);
  for (int c = 0; c < 32; ++c) {
    if (c + 1 < 32) LD(c + 1, an, bn);
#pragma unroll
    for (int i = 0; i < 4; ++i)
#pragma unroll
      for (int j = 0; j < 4; ++j) acc[i][j] = mfma16(a[i], b[j], acc[i][j]);
#pragma unroll
    for (int i = 0; i < 4; ++i) a[i] = an[i];
#pragma unroll
    for (int j = 0; j < 4; ++j) b[j] = bn[j];
  }

#pragma unroll
  for (int i = 0; i < 4; ++i)
#pragma unroll
    for (int j = 0; j < 4; ++j)
#pragma unroll
      for (int r = 0; r < 4; ++r)
        lg[wr + i * 16 + quad * 4 + r][wc + j * 16 + l15] = acc[i][j][r] + outB[bcolv[j]];
  __syncthreads();

  const int row = tid >> 1, half = tid & 1;
  const int cbeg = half ? 48 : 0, cend = half ? 128 : 48;
  float m = -1e30f;
  for (int c = cbeg; c < cend; ++c) m = fmaxf(m, lg[row][c]);
  float s = 0.f;
  for (int c = cbeg; c < cend; ++c) s += __expf(lg[row][c] - m);
  float rinv = 1.f / s;
  float* orow = out + (size_t)(r0 + row) * D_;
  for (int c = cbeg; c < cend; ++c) orow[c] = __expf(lg[row][c] - m) * rinv;

  int tg = targets[(size_t)(r0 + row) * 2 + half];
  int tc = half ? (48 + tg) : tg;
  float ce = -(lg[row][tc] - m - logf(s));
  red2[tid] = 0.5f * ce;
  __syncthreads();
  for (int o = 128; o > 0; o >>= 1) {
    if (tid < o) red2[tid] += red2[tid + o];
    __syncthreads();
  }
  if (tid == 0) atomicAdd(loss, red2[0]);
}

__global__ void finalize_loss(const float* __restrict__ loss, float* __restrict__ out)
{
  out[(size_t)T_ * B_ * D_] = loss[0] * (1.f / (float)(T_ * B_));
}

// ---------------------------------------------------------------------------
extern "C" void kernel_launch(void* const* d_in, const int* in_sizes, int n_in,
                              void* d_out, int out_size, void* d_ws, size_t ws_size,
                              hipStream_t stream)
{
  const float* inSeq = (const float*)d_in[0];
  const int* targets = (const int*)d_in[1];
  const float* W1 = (const float*)d_in[2];
  const float* b1 = (const float*)d_in[3];
  const float* W2 = (const float*)d_in[4];
  const float* b2 = (const float*)d_in[5];
  const float* outW = (const float*)d_in[6];
  const float* outB = (const float*)d_in[7];
  float* out = (float*)d_out;

  // workspace layout: fallback-needed arrays first (~104 MB), then the
  // persistent-only extras (flags + h1 ring) -> ~112 MB total.
  char* w = (char*)d_ws;
  auto alloc = [&](size_t bytes) {
    char* r = w;
    w += (bytes + 255) & ~(size_t)255;
    return r;
  };
  unsigned short* W1p = (unsigned short*)alloc((size_t)4096 * K1_ * 2);
  unsigned short* W2p = (unsigned short*)alloc((size_t)4096 * K2_ * 2);
  unsigned short* xbf = (unsigned short*)alloc((size_t)T_ * B_ * D_ * 2);
  unsigned short* h1b = (unsigned short*)alloc((size_t)2 * B_ * H_ * 2);
  unsigned short* h2all = (unsigned short*)alloc((size_t)(T_ + 1) * B_ * H_ * 2);
  float* c1 = (float*)alloc((size_t)B_ * H_ * 4);
  float* c2 = (float*)alloc((size_t)B_ * H_ * 4);
  unsigned short* outWp = (unsigned short*)alloc((size_t)H_ * D_ * 2);
  float* loss = (float*)alloc(256);
  int* f1 = (int*)alloc(256 * 4);
  int* f2 = (int*)alloc(256 * 4);
  unsigned short* h1r = (unsigned short*)alloc((size_t)R_ * B_ * H_ * 2);

  const bool fits = ((size_t)(w - (char*)d_ws) <= ws_size);
  if (!fits) { f1 = nullptr; f2 = nullptr; h1r = nullptr; }

  prep_misc<<<dim3((T_ * B_ * D_) / 256), dim3(256), 0, stream>>>(
      inSeq, outW, xbf, outWp, h1b, h1r, h2all, c1, c2, loss, f1, f2);
  pack_w<<<dim3(K1_ / 64, 16, 4), dim3(256), 0, stream>>>(W1, W1p, K1_);
  pack_w<<<dim3(K2_ / 64, 16, 4), dim3(256), 0, stream>>>(W2, W2p, K2_);

  hipError_t ce = hipErrorUnknown;
  if (fits) {
    void* kargs[] = {(void*)&xbf, (void*)&W1p, (void*)&W2p, (void*)&b1,
                     (void*)&b2,  (void*)&h1r, (void*)&h2all,
                     (void*)&f1,  (void*)&f2};
    ce = hipLaunchCooperativeKernel((const void*)lstm_persistent,
                                    dim3(512), dim3(256), kargs, 0, stream);
  }
  if (ce != hipSuccess) {
    // Fallback: verified per-phase launch loop.
    (void)hipGetLastError();
    for (int p = 0; p <= T_; ++p)
      phase_kernel<<<dim3(512), dim3(256), 0, stream>>>(
          p, xbf, W1p, W2p, b1, b2, h1b, h2all, c1, c2);
  }

  proj_kernel<<<dim3(256), dim3(256), 0, stream>>>(
      h2all + (size_t)B_ * H_, outWp, outB, targets, out, loss);
  finalize_loss<<<dim3(1), dim3(1), 0, stream>>>(loss, out);
}

// Round 7
// 5726.275 us; speedup vs baseline: 1.0143x; 1.0143x over previous
//
#include <hip/hip_runtime.h>
#include <cstdint>
#include <cstddef>

// Model dims
#define T_ 256
#define B_ 128
#define D_ 128
#define H_ 1024
#define K1_ 1152   // D + H
#define K2_ 2048   // 2H

// h1 ring: 32 write-once-per-window slots; agent-acquire fence every R_ steps
#define R_ 32

typedef __bf16 bf16x8 __attribute__((ext_vector_type(8)));
typedef short s8 __attribute__((ext_vector_type(8)));
typedef float f32x4 __attribute__((ext_vector_type(4)));

__device__ __forceinline__ unsigned short f2bf(float f) {
  unsigned int u = __builtin_bit_cast(unsigned int, f);
  u += 0x7fff + ((u >> 16) & 1);   // RNE
  return (unsigned short)(u >> 16);
}
__device__ __forceinline__ float sigm(float x) { return 1.f / (1.f + __expf(-x)); }
__device__ __forceinline__ float tanh_(float x) { return 1.f - 2.f / (__expf(2.f * x) + 1.f); }

__device__ __forceinline__ f32x4 mfma16(s8 a, s8 b, f32x4 c) {
  return __builtin_amdgcn_mfma_f32_16x16x32_bf16(
      __builtin_bit_cast(bf16x8, a), __builtin_bit_cast(bf16x8, b), c, 0, 0, 0);
}

// Write-through 2B store to the coherence point (L3): producers publish h.
__device__ __forceinline__ void st_bypass_short(unsigned short* p, unsigned int v) {
  asm volatile("global_store_short %0, %1, off sc0 sc1" :: "v"(p), "v"(v) : "memory");
}
// Single-writer flag publish (plain dword, write-through).
__device__ __forceinline__ void st_flag(int* p, int v) {
  asm volatile("global_store_dword %0, %1, off sc0 sc1" :: "v"(p), "v"(v) : "memory");
}

// Wave-parallel wait: 64 lanes each watch 4 flags (dwordx4 bypass load covers
// the whole 256-entry array); done when ALL 256 flags >= want.
__device__ __forceinline__ void wave_wait1(const int* p, int want) {
  for (;;) {
    int4 v;
    asm volatile("global_load_dwordx4 %0, %1, off sc0 sc1\n\ts_waitcnt vmcnt(0)"
                 : "=v"(v) : "v"(p) : "memory");
    int ok = (v.x >= want) && (v.y >= want) && (v.z >= want) && (v.w >= want);
    if (__all(ok)) break;
    __builtin_amdgcn_s_sleep(1);
  }
}
__device__ __forceinline__ void wave_wait2(const int* pa, int wa,
                                           const int* pb, int wb) {
  for (;;) {
    int4 a, b;
    asm volatile("global_load_dwordx4 %0, %2, off sc0 sc1\n\t"
                 "global_load_dwordx4 %1, %3, off sc0 sc1\n\t"
                 "s_waitcnt vmcnt(0)"
                 : "=v"(a), "=v"(b) : "v"(pa), "v"(pb) : "memory");
    int ok = (a.x >= wa) && (a.y >= wa) && (a.z >= wa) && (a.w >= wa) &&
             (b.x >= wb) && (b.y >= wb) && (b.z >= wb) && (b.w >= wb);
    if (__all(ok)) break;
    __builtin_amdgcn_s_sleep(1);
  }
}

// ---------------------------------------------------------------------------
// Prep: convert inSeq -> bf16, pack outW -> [col][k] bf16, zero states/loss,
// zero flags, zero ring slot R_-1 (h1(t=-1)).
// ---------------------------------------------------------------------------
__global__ void prep_misc(const float* __restrict__ inSeq,
                          const float* __restrict__ outW,
                          unsigned short* __restrict__ xbf,
                          unsigned short* __restrict__ outWp,
                          unsigned short* __restrict__ h1b,
                          unsigned short* __restrict__ h1r,
                          unsigned short* __restrict__ h2all,
                          float* __restrict__ c1, float* __restrict__ c2,
                          float* __restrict__ loss,
                          int* __restrict__ f1, int* __restrict__ f2)
{
  int i = blockIdx.x * 256 + threadIdx.x;
  if (i < T_ * B_ * D_) xbf[i] = f2bf(inSeq[i]);
  if (i < B_ * H_) {
    c1[i] = 0.f; c2[i] = 0.f;
    h1b[B_ * H_ + i] = 0;                       // fallback parity-1 buffer
    if (h1r) h1r[(size_t)(R_ - 1) * B_ * H_ + i] = 0;  // ring slot for h1(-1)
    h2all[i] = 0;                               // slot 0 = h2(t=-1)
  }
  if (i < H_ * D_) {          // outWp[c][k] = outW[k][c]
    int c = i >> 10, k = i & 1023;
    outWp[i] = f2bf(outW[(size_t)k * D_ + c]);
  }
  if (f1 && i < 256) { f1[i] = 0; f2[i] = 0; }
  if (i == 0) loss[0] = 0.f;
}

// ---------------------------------------------------------------------------
// Pack LSTM weights: src fp32 [K][4096] (gate-major cols: i|j|f|o blocks of H)
//   -> dst bf16 [4096][K], dst row = 4*j + g  (gate-interleaved, k-major)
// ---------------------------------------------------------------------------
__global__ void pack_w(const float* __restrict__ src, unsigned short* __restrict__ dst, int K)
{
  __shared__ float tile[64][65];
  int k0 = blockIdx.x * 64, j0 = blockIdx.y * 64, g = blockIdx.z;
  int tid = threadIdx.x;
#pragma unroll
  for (int e = 0; e < 16; ++e) {
    int li = e * 256 + tid;
    int kl = li >> 6, jl = li & 63;
    tile[kl][jl] = src[(size_t)(k0 + kl) * 4096 + g * 1024 + j0 + jl];
  }
  __syncthreads();
#pragma unroll
  for (int e = 0; e < 16; ++e) {
    int li = e * 256 + tid;
    int jl = li >> 6, kl = li & 63;
    dst[(size_t)((j0 + jl) * 4 + g) * K + k0 + kl] = f2bf(tile[kl][jl]);
  }
}

// ---------------------------------------------------------------------------
// FALLBACK path (identical to verified kernel): per-phase launches.
// ---------------------------------------------------------------------------
__global__ __launch_bounds__(256, 2) void phase_kernel(
    int p,
    const unsigned short* __restrict__ xbf,
    const unsigned short* __restrict__ W1p,
    const unsigned short* __restrict__ W2p,
    const float* __restrict__ b1,
    const float* __restrict__ b2,
    unsigned short* __restrict__ h1b,
    unsigned short* __restrict__ h2all,
    float* __restrict__ c1,
    float* __restrict__ c2)
{
  __shared__ float red[4][2048];
  const int bid = blockIdx.x;
  const bool isL2 = bid >= 256;
  if (!isL2 && p >= T_) return;
  if (isL2 && p == 0) return;
  const int jb = isL2 ? (bid - 256) : bid;
  const int mt = jb & 1, nt = jb >> 1;
  const int t = isL2 ? (p - 1) : p;
  const int r0 = mt * 64, c0 = nt * 32;
  const int tid = threadIdx.x;
  const int wid = tid >> 6, lane = tid & 63;
  const int quad = lane >> 4, l15 = lane & 15;
  const int kseg = quad * 8;

  const unsigned short* hsrc = h1b + (size_t)((p + 1) & 1) * (B_ * H_);

  f32x4 acc[4][2];
#pragma unroll
  for (int i = 0; i < 4; ++i)
#pragma unroll
    for (int j = 0; j < 2; ++j) acc[i][j] = (f32x4){0.f, 0.f, 0.f, 0.f};

  int arow[4], bcol[2];
#pragma unroll
  for (int i = 0; i < 4; ++i) arow[i] = r0 + i * 16 + l15;
#pragma unroll
  for (int j = 0; j < 2; ++j) bcol[j] = c0 + j * 16 + l15;

  if (!isL2) {
    const unsigned short* xt = xbf + (size_t)t * (B_ * D_);
    const int cpw = 9;
    const int kcbase = wid * cpw;
    s8 a[4], b[2], an[4], bn[2];
    auto LD = [&](int kc, s8* A, s8* Bv) {
      int kk = kc * 32 + kseg;
      if (kk < D_) {
#pragma unroll
        for (int i = 0; i < 4; ++i) A[i] = *(const s8*)(xt + (size_t)arow[i] * D_ + kk);
      } else {
#pragma unroll
        for (int i = 0; i < 4; ++i) A[i] = *(const s8*)(hsrc + (size_t)arow[i] * H_ + (kk - D_));
      }
#pragma unroll
      for (int j = 0; j < 2; ++j) Bv[j] = *(const s8*)(W1p + (size_t)bcol[j] * K1_ + kk);
    };
    LD(kcbase, a, b);
    for (int c = 0; c < cpw; ++c) {
      if (c + 1 < cpw) LD(kcbase + c + 1, an, bn);
#pragma unroll
      for (int i = 0; i < 4; ++i)
#pragma unroll
        for (int j = 0; j < 2; ++j) acc[i][j] = mfma16(a[i], b[j], acc[i][j]);
#pragma unroll
      for (int i = 0; i < 4; ++i) a[i] = an[i];
      b[0] = bn[0]; b[1] = bn[1];
    }
  } else {
    const unsigned short* h2prev = h2all + (size_t)t * (B_ * H_);
    const int cpw = 16;
    const int kcbase = wid * cpw;
    s8 a[4], b[2], an[4], bn[2];
    auto LD = [&](int kc, s8* A, s8* Bv) {
      int kk = kc * 32 + kseg;
      if (kk < H_) {
#pragma unroll
        for (int i = 0; i < 4; ++i) A[i] = *(const s8*)(hsrc + (size_t)arow[i] * H_ + kk);
      } else {
#pragma unroll
        for (int i = 0; i < 4; ++i) A[i] = *(const s8*)(h2prev + (size_t)arow[i] * H_ + (kk - H_));
      }
#pragma unroll
      for (int j = 0; j < 2; ++j) Bv[j] = *(const s8*)(W2p + (size_t)bcol[j] * K2_ + kk);
    };
    LD(kcbase, a, b);
    for (int c = 0; c < cpw; ++c) {
      if (c + 1 < cpw) LD(kcbase + c + 1, an, bn);
#pragma unroll
      for (int i = 0; i < 4; ++i)
#pragma unroll
        for (int j = 0; j < 2; ++j) acc[i][j] = mfma16(a[i], b[j], acc[i][j]);
#pragma unroll
      for (int i = 0; i < 4; ++i) a[i] = an[i];
      b[0] = bn[0]; b[1] = bn[1];
    }
  }

#pragma unroll
  for (int i = 0; i < 4; ++i)
#pragma unroll
    for (int j = 0; j < 2; ++j)
#pragma unroll
      for (int r = 0; r < 4; ++r)
        red[wid][(i * 16 + quad * 4 + r) * 32 + (j * 16 + l15)] = acc[i][j][r];
  __syncthreads();
#pragma unroll
  for (int it = 0; it < 8; ++it) {
    int e = it * 256 + tid;
    red[0][e] = red[0][e] + red[1][e] + red[2][e] + red[3][e];
  }
  __syncthreads();

  const float* bias = isL2 ? b2 : b1;
  float* cst = isL2 ? c2 : c1;
  unsigned short* hout = isL2 ? (h2all + (size_t)(t + 1) * (B_ * H_))
                              : (h1b + (size_t)(p & 1) * (B_ * H_));
#pragma unroll
  for (int it = 0; it < 2; ++it) {
    int s = it * 256 + tid;
    int row = s >> 3, u = s & 7;
    int jg = (c0 >> 2) + u;
    float zi = red[0][row * 32 + u * 4 + 0] + bias[0 * H_ + jg];
    float zj = red[0][row * 32 + u * 4 + 1] + bias[1 * H_ + jg];
    float zf = red[0][row * 32 + u * 4 + 2] + bias[2 * H_ + jg];
    float zo = red[0][row * 32 + u * 4 + 3] + bias[3 * H_ + jg];
    int rg = r0 + row;
    float co = cst[(size_t)rg * H_ + jg];
    float cn = co * sigm(zf + 1.0f) + sigm(zi) * tanh_(zj);
    float hn = tanh_(cn) * sigm(zo);
    cst[(size_t)rg * H_ + jg] = cn;
    hout[(size_t)rg * H_ + jg] = f2bf(hn);
  }
}

// ---------------------------------------------------------------------------
// PERSISTENT kernel (round-5 structure, ROLE-INTERLEAVED block mapping):
//  - isL2 = bid & 1, jb = bid >> 1: consecutive block IDs are one L1 + one L2
//    block, so each CU (which hosts two consecutive blocks) pairs an L1 tile
//    with an L2 tile. While the L1 block spins on the h1 barrier, the L2
//    block's loads/MFMAs keep the CU busy, and vice versa -> cross-layer
//    overlap that the 0..255/256..511 mapping silently destroyed.
//  - everything else identical to the verified round-5 kernel:
//    single-writer flags, wave-parallel polling, per-wave selective waits in
//    the L2 role, write-through h stores + plain cached loads, 32-slot h1
//    ring with one agent-acquire fence per 32 steps, weights + cell state
//    register-resident, depth-2 chunk prefetch (bitwise-identical numerics).
// ---------------------------------------------------------------------------
__global__ __launch_bounds__(256, 2) void lstm_persistent(
    const unsigned short* __restrict__ xbf,
    const unsigned short* __restrict__ W1p,
    const unsigned short* __restrict__ W2p,
    const float* __restrict__ b1,
    const float* __restrict__ b2,
    unsigned short* __restrict__ h1r,
    unsigned short* __restrict__ h2all,
    int* __restrict__ f1,
    int* __restrict__ f2)
{
  __shared__ float red[4][2048];
  const int bid = blockIdx.x;
  const bool isL2 = (bid & 1) != 0;      // role interleave (the one change)
  const int jb = bid >> 1;               // tile id 0..255 within the layer
  const int mt = jb & 1, nt = jb >> 1;
  const int r0 = mt * 64, c0 = nt * 32;
  const int tid = threadIdx.x;
  const int wid = tid >> 6, lane = tid & 63;
  const int quad = lane >> 4, l15 = lane & 15;
  const int kseg = quad * 8;
  const int lane4 = lane * 4;

  int arow[4], bcol[2];
#pragma unroll
  for (int i = 0; i < 4; ++i) arow[i] = r0 + i * 16 + l15;
#pragma unroll
  for (int j = 0; j < 2; ++j) bcol[j] = c0 + j * 16 + l15;

  // Register-resident epilogue state (fixed (row,unit) per thread).
  const float* bias = isL2 ? b2 : b1;
  int ridx[2];
  unsigned hoff[2];
  float bz[2][4], creg[2];
#pragma unroll
  for (int it = 0; it < 2; ++it) {
    int s = it * 256 + tid;
    int row = s >> 3, u = s & 7;
    int jg = (c0 >> 2) + u;
    ridx[it] = row * 32 + u * 4;
    hoff[it] = (unsigned)((r0 + row) * H_ + jg);
#pragma unroll
    for (int g = 0; g < 4; ++g) bz[it][g] = bias[g * H_ + jg];
    creg[it] = 0.f;
  }

  if (!isL2) {
    // ----- layer-1 role: K = 1152, 9 chunks/wave; weights -> 72 VGPR -----
    const int kcbase = wid * 9;
    s8 bw[9][2];
#pragma unroll
    for (int c = 0; c < 9; ++c) {
      int kk = (kcbase + c) * 32 + kseg;
      bw[c][0] = *(const s8*)(W1p + (size_t)bcol[0] * K1_ + kk);
      bw[c][1] = *(const s8*)(W1p + (size_t)bcol[1] * K1_ + kk);
    }
#pragma unroll
    for (int c = 0; c < 9; ++c)
      asm volatile("" : "+v"(bw[c][0]), "+v"(bw[c][1]));   // pin in regs

    for (int t = 0; t < T_; ++t) {
      wave_wait2(f1 + lane4, t, f2 + lane4, t - (R_ - 1));
      if ((t & (R_ - 1)) == 0 && t)
        __builtin_amdgcn_fence(__ATOMIC_ACQUIRE, "agent"); // flush >=R_-old lines

      const unsigned short* hsrc = h1r + (size_t)((t + R_ - 1) & (R_ - 1)) * (B_ * H_);
      const unsigned short* xt = xbf + (size_t)t * (B_ * D_);
      f32x4 acc[4][2];
#pragma unroll
      for (int i = 0; i < 4; ++i)
#pragma unroll
        for (int j = 0; j < 2; ++j) acc[i][j] = (f32x4){0.f, 0.f, 0.f, 0.f};
      s8 a[4], an[4];
      auto LD = [&](int kc, s8* A) {
        int kk = kc * 32 + kseg;
        if (kk < D_) {
#pragma unroll
          for (int i = 0; i < 4; ++i) A[i] = *(const s8*)(xt + (size_t)arow[i] * D_ + kk);
        } else {
#pragma unroll
          for (int i = 0; i < 4; ++i) A[i] = *(const s8*)(hsrc + (size_t)arow[i] * H_ + (kk - D_));
        }
      };
      LD(kcbase, a);
#pragma unroll
      for (int c = 0; c < 9; ++c) {
        if (c + 1 < 9) LD(kcbase + c + 1, an);
#pragma unroll
        for (int i = 0; i < 4; ++i)
#pragma unroll
          for (int j = 0; j < 2; ++j) acc[i][j] = mfma16(a[i], bw[c][j], acc[i][j]);
#pragma unroll
        for (int i = 0; i < 4; ++i) a[i] = an[i];
      }
#pragma unroll
      for (int i = 0; i < 4; ++i)
#pragma unroll
        for (int j = 0; j < 2; ++j)
#pragma unroll
          for (int r = 0; r < 4; ++r)
            red[wid][(i * 16 + quad * 4 + r) * 32 + (j * 16 + l15)] = acc[i][j][r];
      __syncthreads();
#pragma unroll
      for (int it = 0; it < 8; ++it) {
        int e = it * 256 + tid;
        red[0][e] = red[0][e] + red[1][e] + red[2][e] + red[3][e];
      }
      __syncthreads();
      unsigned short* hout = h1r + (size_t)(t & (R_ - 1)) * (B_ * H_);
#pragma unroll
      for (int it = 0; it < 2; ++it) {
        float zi = red[0][ridx[it] + 0] + bz[it][0];
        float zj = red[0][ridx[it] + 1] + bz[it][1];
        float zf = red[0][ridx[it] + 2] + bz[it][2];
        float zo = red[0][ridx[it] + 3] + bz[it][3];
        float cn = creg[it] * sigm(zf + 1.0f) + sigm(zi) * tanh_(zj);
        float hn = tanh_(cn) * sigm(zo);
        creg[it] = cn;
        st_bypass_short(hout + hoff[it], (unsigned int)f2bf(hn));
      }
      asm volatile("s_waitcnt vmcnt(0)" ::: "memory");  // h1(t) at L3
      __syncthreads();                                  // all threads drained
      if (tid == 0) st_flag(f1 + jb, t + 1);            // single-writer publish
    }
  } else {
    // ----- layer-2 role: K = 2048, 16 chunks/wave; weights -> 128 VGPR -----
    const int kcbase = wid * 16;
    s8 bw[16][2];
#pragma unroll
    for (int c = 0; c < 16; ++c) {
      int kk = (kcbase + c) * 32 + kseg;
      bw[c][0] = *(const s8*)(W2p + (size_t)bcol[0] * K2_ + kk);
      bw[c][1] = *(const s8*)(W2p + (size_t)bcol[1] * K2_ + kk);
    }
#pragma unroll
    for (int c = 0; c < 16; ++c)
      asm volatile("" : "+v"(bw[c][0]), "+v"(bw[c][1]));   // pin in regs

    for (int t = 0; t < T_; ++t) {
      // per-wave selective waits: waves 0-1 read h1(t); waves 2-3 read h2(t-1)
      if (wid < 2) wave_wait1(f1 + lane4, t + 1);
      else         wave_wait1(f2 + lane4, t);
      if ((t & (R_ - 1)) == 0 && t)
        __builtin_amdgcn_fence(__ATOMIC_ACQUIRE, "agent");

      const unsigned short* hsrc = h1r + (size_t)(t & (R_ - 1)) * (B_ * H_);
      const unsigned short* h2prev = h2all + (size_t)t * (B_ * H_);
      f32x4 acc[4][2];
#pragma unroll
      for (int i = 0; i < 4; ++i)
#pragma unroll
        for (int j = 0; j < 2; ++j) acc[i][j] = (f32x4){0.f, 0.f, 0.f, 0.f};
      s8 a[4], an[4];
      auto LD = [&](int kc, s8* A) {
        int kk = kc * 32 + kseg;
        if (kk < H_) {
#pragma unroll
          for (int i = 0; i < 4; ++i) A[i] = *(const s8*)(hsrc + (size_t)arow[i] * H_ + kk);
        } else {
#pragma unroll
          for (int i = 0; i < 4; ++i) A[i] = *(const s8*)(h2prev + (size_t)arow[i] * H_ + (kk - H_));
        }
      };
      LD(kcbase, a);
#pragma unroll
      for (int c = 0; c < 16; ++c) {
        if (c + 1 < 16) LD(kcbase + c + 1, an);
#pragma unroll
        for (int i = 0; i < 4; ++i)
#pragma unroll
          for (int j = 0; j < 2; ++j) acc[i][j] = mfma16(a[i], bw[c][j], acc[i][j]);
#pragma unroll
        for (int i = 0; i < 4; ++i) a[i] = an[i];
      }
#pragma unroll
      for (int i = 0; i < 4; ++i)
#pragma unroll
        for (int j = 0; j < 2; ++j)
#pragma unroll
          for (int r = 0; r < 4; ++r)
            red[wid][(i * 16 + quad * 4 + r) * 32 + (j * 16 + l15)] = acc[i][j][r];
      __syncthreads();
#pragma unroll
      for (int it = 0; it < 8; ++it) {
        int e = it * 256 + tid;
        red[0][e] = red[0][e] + red[1][e] + red[2][e] + red[3][e];
      }
      __syncthreads();
      unsigned short* hout = h2all + (size_t)(t + 1) * (B_ * H_);
#pragma unroll
      for (int it = 0; it < 2; ++it) {
        float zi = red[0][ridx[it] + 0] + bz[it][0];
        float zj = red[0][ridx[it] + 1] + bz[it][1];
        float zf = red[0][ridx[it] + 2] + bz[it][2];
        float zo = red[0][ridx[it] + 3] + bz[it][3];
        float cn = creg[it] * sigm(zf + 1.0f) + sigm(zi) * tanh_(zj);
        float hn = tanh_(cn) * sigm(zo);
        creg[it] = cn;
        st_bypass_short(hout + hoff[it], (unsigned int)f2bf(hn));
      }
      asm volatile("s_waitcnt vmcnt(0)" ::: "memory");
      __syncthreads();
      if (tid == 0) st_flag(f2 + jb, t + 1);            // single-writer publish
    }
  }
}

// ---------------------------------------------------------------------------
// Tail: logits = h2 @ outW + outB, dual softmax, probs out, CE loss.
// ---------------------------------------------------------------------------
__global__ __launch_bounds__(256, 1) void proj_kernel(
    const unsigned short* __restrict__ h2flat,
    const unsigned short* __restrict__ outWp,
    const float* __restrict__ outB,
    const int* __restrict__ targets,
    float* __restrict__ out,
    float* __restrict__ loss)
{
  __shared__ float lg[128][129];
  __shared__ float red2[256];
  const int r0 = blockIdx.x * 128;
  const int tid = threadIdx.x;
  const int wid = tid >> 6, lane = tid & 63;
  const int quad = lane >> 4, l15 = lane & 15;
  const int wr = (wid & 1) * 64, wc = (wid >> 1) * 64;
  const int kseg = quad * 8;

  f32x4 acc[4][4];
#pragma unroll
  for (int i = 0; i < 4; ++i)
#pragma unroll
    for (int j = 0; j < 4; ++j) acc[i][j] = (f32x4){0.f, 0.f, 0.f, 0.f};

  int arow[4], bcolv[4];
#pragma unroll
  for (int i = 0; i < 4; ++i) arow[i] = r0 + wr + i * 16 + l15;
#pragma unroll
  for (int j = 0; j < 4; ++j) bcolv[j] = wc + j * 16 + l15;

  s8 a[4], b[4], an[4], bn[4];
  auto LD = [&](int kc, s8* A, s8* Bv) {
    int kk = kc * 32 + kseg;
#pragma unroll
    for (int i = 0; i < 4; ++i) A[i] = *(const s8*)(h2flat + (size_t)arow[i] * H_ + kk);
#pragma unroll
    for (int j = 0; j < 4; ++j) Bv[j] = *(const s8*)(outWp + (size_t)bcolv[j] * H_ + kk);
  };
  LD(0, a, b);
  for (int c = 0; c < 32; ++c) {
    if (c + 1 < 32) LD(c + 1, an, bn);
#pragma unroll
    for (int i = 0; i < 4; ++i)
#pragma unroll
      for (int j = 0; j < 4; ++j) acc[i][j] = mfma16(a[i], b[j], acc[i][j]);
#pragma unroll
    for (int i = 0; i < 4; ++i) a[i] = an[i];
#pragma unroll
    for (int j = 0; j < 4; ++j) b[j] = bn[j];
  }

#pragma unroll
  for (int i = 0; i < 4; ++i)
#pragma unroll
    for (int j = 0; j < 4; ++j)
#pragma unroll
      for (int r = 0; r < 4; ++r)
        lg[wr + i * 16 + quad * 4 + r][wc + j * 16 + l15] = acc[i][j][r] + outB[bcolv[j]];
  __syncthreads();

  const int row = tid >> 1, half = tid & 1;
  const int cbeg = half ? 48 : 0, cend = half ? 128 : 48;
  float m = -1e30f;
  for (int c = cbeg; c < cend; ++c) m = fmaxf(m, lg[row][c]);
  float s = 0.f;
  for (int c = cbeg; c < cend; ++c) s += __expf(lg[row][c] - m);
  float rinv = 1.f / s;
  float* orow = out + (size_t)(r0 + row) * D_;
  for (int c = cbeg; c < cend; ++c) orow[c] = __expf(lg[row][c] - m) * rinv;

  int tg = targets[(size_t)(r0 + row) * 2 + half];
  int tc = half ? (48 + tg) : tg;
  float ce = -(lg[row][tc] - m - logf(s));
  red2[tid] = 0.5f * ce;
  __syncthreads();
  for (int o = 128; o > 0; o >>= 1) {
    if (tid < o) red2[tid] += red2[tid + o];
    __syncthreads();
  }
  if (tid == 0) atomicAdd(loss, red2[0]);
}

__global__ void finalize_loss(const float* __restrict__ loss, float* __restrict__ out)
{
  out[(size_t)T_ * B_ * D_] = loss[0] * (1.f / (float)(T_ * B_));
}

// ---------------------------------------------------------------------------
extern "C" void kernel_launch(void* const* d_in, const int* in_sizes, int n_in,
                              void* d_out, int out_size, void* d_ws, size_t ws_size,
                              hipStream_t stream)
{
  const float* inSeq = (const float*)d_in[0];
  const int* targets = (const int*)d_in[1];
  const float* W1 = (const float*)d_in[2];
  const float* b1 = (const float*)d_in[3];
  const float* W2 = (const float*)d_in[4];
  const float* b2 = (const float*)d_in[5];
  const float* outW = (const float*)d_in[6];
  const float* outB = (const float*)d_in[7];
  float* out = (float*)d_out;

  // workspace layout: fallback-needed arrays first (~104 MB), then the
  // persistent-only extras (flags + h1 ring) -> ~112 MB total.
  char* w = (char*)d_ws;
  auto alloc = [&](size_t bytes) {
    char* r = w;
    w += (bytes + 255) & ~(size_t)255;
    return r;
  };
  unsigned short* W1p = (unsigned short*)alloc((size_t)4096 * K1_ * 2);
  unsigned short* W2p = (unsigned short*)alloc((size_t)4096 * K2_ * 2);
  unsigned short* xbf = (unsigned short*)alloc((size_t)T_ * B_ * D_ * 2);
  unsigned short* h1b = (unsigned short*)alloc((size_t)2 * B_ * H_ * 2);
  unsigned short* h2all = (unsigned short*)alloc((size_t)(T_ + 1) * B_ * H_ * 2);
  float* c1 = (float*)alloc((size_t)B_ * H_ * 4);
  float* c2 = (float*)alloc((size_t)B_ * H_ * 4);
  unsigned short* outWp = (unsigned short*)alloc((size_t)H_ * D_ * 2);
  float* loss = (float*)alloc(256);
  int* f1 = (int*)alloc(256 * 4);
  int* f2 = (int*)alloc(256 * 4);
  unsigned short* h1r = (unsigned short*)alloc((size_t)R_ * B_ * H_ * 2);

  const bool fits = ((size_t)(w - (char*)d_ws) <= ws_size);
  if (!fits) { f1 = nullptr; f2 = nullptr; h1r = nullptr; }

  prep_misc<<<dim3((T_ * B_ * D_) / 256), dim3(256), 0, stream>>>(
      inSeq, outW, xbf, outWp, h1b, h1r, h2all, c1, c2, loss, f1, f2);
  pack_w<<<dim3(K1_ / 64, 16, 4), dim3(256), 0, stream>>>(W1, W1p, K1_);
  pack_w<<<dim3(K2_ / 64, 16, 4), dim3(256), 0, stream>>>(W2, W2p, K2_);

  hipError_t ce = hipErrorUnknown;
  if (fits) {
    void* kargs[] = {(void*)&xbf, (void*)&W1p, (void*)&W2p, (void*)&b1,
                     (void*)&b2,  (void*)&h1r, (void*)&h2all,
                     (void*)&f1,  (void*)&f2};
    ce = hipLaunchCooperativeKernel((const void*)lstm_persistent,
                                    dim3(512), dim3(256), kargs, 0, stream);
  }
  if (ce != hipSuccess) {
    // Fallback: verified per-phase launch loop.
    (void)hipGetLastError();
    for (int p = 0; p <= T_; ++p)
      phase_kernel<<<dim3(512), dim3(256), 0, stream>>>(
          p, xbf, W1p, W2p, b1, b2, h1b, h2all, c1, c2);
  }

  proj_kernel<<<dim3(256), dim3(256), 0, stream>>>(
      h2all + (size_t)B_ * H_, outWp, outB, targets, out, loss);
  finalize_loss<<<dim3(1), dim3(1), 0, stream>>>(loss, out);
}

// Round 8
// 5515.968 us; speedup vs baseline: 1.0530x; 1.0381x over previous
//
#include <hip/hip_runtime.h>
#include <cstdint>
#include <cstddef>

// Model dims
#define T_ 256
#define B_ 128
#define D_ 128
#define H_ 1024
#define K1_ 1152   // D + H
#define K2_ 2048   // 2H

// h1 ring: 32 write-once-per-window slots; agent-acquire fence every R_ steps
#define R_ 32

typedef __bf16 bf16x8 __attribute__((ext_vector_type(8)));
typedef short s8 __attribute__((ext_vector_type(8)));
typedef float f32x4 __attribute__((ext_vector_type(4)));

__device__ __forceinline__ unsigned short f2bf(float f) {
  unsigned int u = __builtin_bit_cast(unsigned int, f);
  u += 0x7fff + ((u >> 16) & 1);   // RNE
  return (unsigned short)(u >> 16);
}
__device__ __forceinline__ float sigm(float x) { return 1.f / (1.f + __expf(-x)); }
__device__ __forceinline__ float tanh_(float x) { return 1.f - 2.f / (__expf(2.f * x) + 1.f); }

__device__ __forceinline__ f32x4 mfma16(s8 a, s8 b, f32x4 c) {
  return __builtin_amdgcn_mfma_f32_16x16x32_bf16(
      __builtin_bit_cast(bf16x8, a), __builtin_bit_cast(bf16x8, b), c, 0, 0, 0);
}

// Write-through 2B store to the coherence point (L3): producers publish h.
__device__ __forceinline__ void st_bypass_short(unsigned short* p, unsigned int v) {
  asm volatile("global_store_short %0, %1, off sc0 sc1" :: "v"(p), "v"(v) : "memory");
}
// Single-writer flag publish (plain dword, write-through).
__device__ __forceinline__ void st_flag(int* p, int v) {
  asm volatile("global_store_dword %0, %1, off sc0 sc1" :: "v"(p), "v"(v) : "memory");
}

// Wave-parallel wait: 64 lanes each watch 4 flags (dwordx4 bypass load covers
// the whole 256-entry array); done when ALL 256 flags >= want.
__device__ __forceinline__ void wave_wait1(const int* p, int want) {
  for (;;) {
    int4 v;
    asm volatile("global_load_dwordx4 %0, %1, off sc0 sc1\n\ts_waitcnt vmcnt(0)"
                 : "=v"(v) : "v"(p) : "memory");
    int ok = (v.x >= want) && (v.y >= want) && (v.z >= want) && (v.w >= want);
    if (__all(ok)) break;
    __builtin_amdgcn_s_sleep(1);
  }
}
__device__ __forceinline__ void wave_wait2(const int* pa, int wa,
                                           const int* pb, int wb) {
  for (;;) {
    int4 a, b;
    asm volatile("global_load_dwordx4 %0, %2, off sc0 sc1\n\t"
                 "global_load_dwordx4 %1, %3, off sc0 sc1\n\t"
                 "s_waitcnt vmcnt(0)"
                 : "=v"(a), "=v"(b) : "v"(pa), "v"(pb) : "memory");
    int ok = (a.x >= wa) && (a.y >= wa) && (a.z >= wa) && (a.w >= wa) &&
             (b.x >= wb) && (b.y >= wb) && (b.z >= wb) && (b.w >= wb);
    if (__all(ok)) break;
    __builtin_amdgcn_s_sleep(1);
  }
}

// ---------------------------------------------------------------------------
// Prep: convert inSeq -> bf16, pack outW -> [col][k] bf16, zero states/loss,
// zero flags, zero ring slot R_-1 (h1(t=-1)).
// ---------------------------------------------------------------------------
__global__ void prep_misc(const float* __restrict__ inSeq,
                          const float* __restrict__ outW,
                          unsigned short* __restrict__ xbf,
                          unsigned short* __restrict__ outWp,
                          unsigned short* __restrict__ h1b,
                          unsigned short* __restrict__ h1r,
                          unsigned short* __restrict__ h2all,
                          float* __restrict__ c1, float* __restrict__ c2,
                          float* __restrict__ loss,
                          int* __restrict__ f1, int* __restrict__ f2)
{
  int i = blockIdx.x * 256 + threadIdx.x;
  if (i < T_ * B_ * D_) xbf[i] = f2bf(inSeq[i]);
  if (i < B_ * H_) {
    c1[i] = 0.f; c2[i] = 0.f;
    h1b[B_ * H_ + i] = 0;                       // fallback parity-1 buffer
    if (h1r) h1r[(size_t)(R_ - 1) * B_ * H_ + i] = 0;  // ring slot for h1(-1)
    h2all[i] = 0;                               // slot 0 = h2(t=-1)
  }
  if (i < H_ * D_) {          // outWp[c][k] = outW[k][c]
    int c = i >> 10, k = i & 1023;
    outWp[i] = f2bf(outW[(size_t)k * D_ + c]);
  }
  if (f1 && i < 256) { f1[i] = 0; f2[i] = 0; }
  if (i == 0) loss[0] = 0.f;
}

// ---------------------------------------------------------------------------
// Pack LSTM weights: src fp32 [K][4096] (gate-major cols: i|j|f|o blocks of H)
//   -> dst bf16 [4096][K], dst row = 4*j + g  (gate-interleaved, k-major)
// ---------------------------------------------------------------------------
__global__ void pack_w(const float* __restrict__ src, unsigned short* __restrict__ dst, int K)
{
  __shared__ float tile[64][65];
  int k0 = blockIdx.x * 64, j0 = blockIdx.y * 64, g = blockIdx.z;
  int tid = threadIdx.x;
#pragma unroll
  for (int e = 0; e < 16; ++e) {
    int li = e * 256 + tid;
    int kl = li >> 6, jl = li & 63;
    tile[kl][jl] = src[(size_t)(k0 + kl) * 4096 + g * 1024 + j0 + jl];
  }
  __syncthreads();
#pragma unroll
  for (int e = 0; e < 16; ++e) {
    int li = e * 256 + tid;
    int jl = li >> 6, kl = li & 63;
    dst[(size_t)((j0 + jl) * 4 + g) * K + k0 + kl] = f2bf(tile[kl][jl]);
  }
}

// ---------------------------------------------------------------------------
// FALLBACK path (identical to verified kernel): per-phase launches.
// ---------------------------------------------------------------------------
__global__ __launch_bounds__(256, 2) void phase_kernel(
    int p,
    const unsigned short* __restrict__ xbf,
    const unsigned short* __restrict__ W1p,
    const unsigned short* __restrict__ W2p,
    const float* __restrict__ b1,
    const float* __restrict__ b2,
    unsigned short* __restrict__ h1b,
    unsigned short* __restrict__ h2all,
    float* __restrict__ c1,
    float* __restrict__ c2)
{
  __shared__ float red[4][2048];
  const int bid = blockIdx.x;
  const bool isL2 = bid >= 256;
  if (!isL2 && p >= T_) return;
  if (isL2 && p == 0) return;
  const int jb = isL2 ? (bid - 256) : bid;
  const int mt = jb & 1, nt = jb >> 1;
  const int t = isL2 ? (p - 1) : p;
  const int r0 = mt * 64, c0 = nt * 32;
  const int tid = threadIdx.x;
  const int wid = tid >> 6, lane = tid & 63;
  const int quad = lane >> 4, l15 = lane & 15;
  const int kseg = quad * 8;

  const unsigned short* hsrc = h1b + (size_t)((p + 1) & 1) * (B_ * H_);

  f32x4 acc[4][2];
#pragma unroll
  for (int i = 0; i < 4; ++i)
#pragma unroll
    for (int j = 0; j < 2; ++j) acc[i][j] = (f32x4){0.f, 0.f, 0.f, 0.f};

  int arow[4], bcol[2];
#pragma unroll
  for (int i = 0; i < 4; ++i) arow[i] = r0 + i * 16 + l15;
#pragma unroll
  for (int j = 0; j < 2; ++j) bcol[j] = c0 + j * 16 + l15;

  if (!isL2) {
    const unsigned short* xt = xbf + (size_t)t * (B_ * D_);
    const int cpw = 9;
    const int kcbase = wid * cpw;
    s8 a[4], b[2], an[4], bn[2];
    auto LD = [&](int kc, s8* A, s8* Bv) {
      int kk = kc * 32 + kseg;
      if (kk < D_) {
#pragma unroll
        for (int i = 0; i < 4; ++i) A[i] = *(const s8*)(xt + (size_t)arow[i] * D_ + kk);
      } else {
#pragma unroll
        for (int i = 0; i < 4; ++i) A[i] = *(const s8*)(hsrc + (size_t)arow[i] * H_ + (kk - D_));
      }
#pragma unroll
      for (int j = 0; j < 2; ++j) Bv[j] = *(const s8*)(W1p + (size_t)bcol[j] * K1_ + kk);
    };
    LD(kcbase, a, b);
    for (int c = 0; c < cpw; ++c) {
      if (c + 1 < cpw) LD(kcbase + c + 1, an, bn);
#pragma unroll
      for (int i = 0; i < 4; ++i)
#pragma unroll
        for (int j = 0; j < 2; ++j) acc[i][j] = mfma16(a[i], b[j], acc[i][j]);
#pragma unroll
      for (int i = 0; i < 4; ++i) a[i] = an[i];
      b[0] = bn[0]; b[1] = bn[1];
    }
  } else {
    const unsigned short* h2prev = h2all + (size_t)t * (B_ * H_);
    const int cpw = 16;
    const int kcbase = wid * cpw;
    s8 a[4], b[2], an[4], bn[2];
    auto LD = [&](int kc, s8* A, s8* Bv) {
      int kk = kc * 32 + kseg;
      if (kk < H_) {
#pragma unroll
        for (int i = 0; i < 4; ++i) A[i] = *(const s8*)(hsrc + (size_t)arow[i] * H_ + kk);
      } else {
#pragma unroll
        for (int i = 0; i < 4; ++i) A[i] = *(const s8*)(h2prev + (size_t)arow[i] * H_ + (kk - H_));
      }
#pragma unroll
      for (int j = 0; j < 2; ++j) Bv[j] = *(const s8*)(W2p + (size_t)bcol[j] * K2_ + kk);
    };
    LD(kcbase, a, b);
    for (int c = 0; c < cpw; ++c) {
      if (c + 1 < cpw) LD(kcbase + c + 1, an, bn);
#pragma unroll
      for (int i = 0; i < 4; ++i)
#pragma unroll
        for (int j = 0; j < 2; ++j) acc[i][j] = mfma16(a[i], b[j], acc[i][j]);
#pragma unroll
      for (int i = 0; i < 4; ++i) a[i] = an[i];
      b[0] = bn[0]; b[1] = bn[1];
    }
  }

#pragma unroll
  for (int i = 0; i < 4; ++i)
#pragma unroll
    for (int j = 0; j < 2; ++j)
#pragma unroll
      for (int r = 0; r < 4; ++r)
        red[wid][(i * 16 + quad * 4 + r) * 32 + (j * 16 + l15)] = acc[i][j][r];
  __syncthreads();
#pragma unroll
  for (int it = 0; it < 8; ++it) {
    int e = it * 256 + tid;
    red[0][e] = red[0][e] + red[1][e] + red[2][e] + red[3][e];
  }
  __syncthreads();

  const float* bias = isL2 ? b2 : b1;
  float* cst = isL2 ? c2 : c1;
  unsigned short* hout = isL2 ? (h2all + (size_t)(t + 1) * (B_ * H_))
                              : (h1b + (size_t)(p & 1) * (B_ * H_));
#pragma unroll
  for (int it = 0; it < 2; ++it) {
    int s = it * 256 + tid;
    int row = s >> 3, u = s & 7;
    int jg = (c0 >> 2) + u;
    float zi = red[0][row * 32 + u * 4 + 0] + bias[0 * H_ + jg];
    float zj = red[0][row * 32 + u * 4 + 1] + bias[1 * H_ + jg];
    float zf = red[0][row * 32 + u * 4 + 2] + bias[2 * H_ + jg];
    float zo = red[0][row * 32 + u * 4 + 3] + bias[3 * H_ + jg];
    int rg = r0 + row;
    float co = cst[(size_t)rg * H_ + jg];
    float cn = co * sigm(zf + 1.0f) + sigm(zi) * tanh_(zj);
    float hn = tanh_(cn) * sigm(zo);
    cst[(size_t)rg * H_ + jg] = cn;
    hout[(size_t)rg * H_ + jg] = f2bf(hn);
  }
}

// ---------------------------------------------------------------------------
// PERSISTENT kernel (round-5 structure; REGISTER-BUDGET FIX):
//  amdgpu_waves_per_eu(2,2) pins the allocator to the 2-waves/EU design point
//  (256 VGPRs/wave budget) so the L2-role weight slab (bw[16][2] = 128 VGPR)
//  actually stays register-resident. Rounds 1-7 allocated only 128 VGPRs ->
//  weights were re-fetched every chunk, a dependent load on the MFMA chain
//  every step (the sync-independent ~15us/step residual).
//  Occupancy unchanged: 2 blocks/CU x 4 waves = 8 waves/CU = 2/EU.
//  All sync/data structure identical to the verified round-5 kernel.
// ---------------------------------------------------------------------------
__global__ __attribute__((amdgpu_waves_per_eu(2, 2))) __launch_bounds__(256)
void lstm_persistent(
    const unsigned short* __restrict__ xbf,
    const unsigned short* __restrict__ W1p,
    const unsigned short* __restrict__ W2p,
    const float* __restrict__ b1,
    const float* __restrict__ b2,
    unsigned short* __restrict__ h1r,
    unsigned short* __restrict__ h2all,
    int* __restrict__ f1,
    int* __restrict__ f2)
{
  __shared__ float red[4][2048];
  const int bid = blockIdx.x;
  const bool isL2 = bid >= 256;
  const int jb = isL2 ? (bid - 256) : bid;
  const int mt = jb & 1, nt = jb >> 1;
  const int r0 = mt * 64, c0 = nt * 32;
  const int tid = threadIdx.x;
  const int wid = tid >> 6, lane = tid & 63;
  const int quad = lane >> 4, l15 = lane & 15;
  const int kseg = quad * 8;
  const int lane4 = lane * 4;

  int arow[4], bcol[2];
#pragma unroll
  for (int i = 0; i < 4; ++i) arow[i] = r0 + i * 16 + l15;
#pragma unroll
  for (int j = 0; j < 2; ++j) bcol[j] = c0 + j * 16 + l15;

  // Register-resident epilogue state (fixed (row,unit) per thread).
  const float* bias = isL2 ? b2 : b1;
  int ridx[2];
  unsigned hoff[2];
  float bz[2][4], creg[2];
#pragma unroll
  for (int it = 0; it < 2; ++it) {
    int s = it * 256 + tid;
    int row = s >> 3, u = s & 7;
    int jg = (c0 >> 2) + u;
    ridx[it] = row * 32 + u * 4;
    hoff[it] = (unsigned)((r0 + row) * H_ + jg);
#pragma unroll
    for (int g = 0; g < 4; ++g) bz[it][g] = bias[g * H_ + jg];
    creg[it] = 0.f;
  }

  if (!isL2) {
    // ----- layer-1 role: K = 1152, 9 chunks/wave; weights -> 72 VGPR -----
    const int kcbase = wid * 9;
    s8 bw[9][2];
#pragma unroll
    for (int c = 0; c < 9; ++c) {
      int kk = (kcbase + c) * 32 + kseg;
      bw[c][0] = *(const s8*)(W1p + (size_t)bcol[0] * K1_ + kk);
      bw[c][1] = *(const s8*)(W1p + (size_t)bcol[1] * K1_ + kk);
    }
#pragma unroll
    for (int c = 0; c < 9; ++c)
      asm volatile("" : "+v"(bw[c][0]), "+v"(bw[c][1]));   // pin in regs

    for (int t = 0; t < T_; ++t) {
      wave_wait2(f1 + lane4, t, f2 + lane4, t - (R_ - 1));
      if ((t & (R_ - 1)) == 0 && t)
        __builtin_amdgcn_fence(__ATOMIC_ACQUIRE, "agent"); // flush >=R_-old lines

      const unsigned short* hsrc = h1r + (size_t)((t + R_ - 1) & (R_ - 1)) * (B_ * H_);
      const unsigned short* xt = xbf + (size_t)t * (B_ * D_);
      f32x4 acc[4][2];
#pragma unroll
      for (int i = 0; i < 4; ++i)
#pragma unroll
        for (int j = 0; j < 2; ++j) acc[i][j] = (f32x4){0.f, 0.f, 0.f, 0.f};
      s8 a[4], an[4];
      auto LD = [&](int kc, s8* A) {
        int kk = kc * 32 + kseg;
        if (kk < D_) {
#pragma unroll
          for (int i = 0; i < 4; ++i) A[i] = *(const s8*)(xt + (size_t)arow[i] * D_ + kk);
        } else {
#pragma unroll
          for (int i = 0; i < 4; ++i) A[i] = *(const s8*)(hsrc + (size_t)arow[i] * H_ + (kk - D_));
        }
      };
      LD(kcbase, a);
#pragma unroll
      for (int c = 0; c < 9; ++c) {
        if (c + 1 < 9) LD(kcbase + c + 1, an);
#pragma unroll
        for (int i = 0; i < 4; ++i)
#pragma unroll
          for (int j = 0; j < 2; ++j) acc[i][j] = mfma16(a[i], bw[c][j], acc[i][j]);
#pragma unroll
        for (int i = 0; i < 4; ++i) a[i] = an[i];
      }
#pragma unroll
      for (int i = 0; i < 4; ++i)
#pragma unroll
        for (int j = 0; j < 2; ++j)
#pragma unroll
          for (int r = 0; r < 4; ++r)
            red[wid][(i * 16 + quad * 4 + r) * 32 + (j * 16 + l15)] = acc[i][j][r];
      __syncthreads();
#pragma unroll
      for (int it = 0; it < 8; ++it) {
        int e = it * 256 + tid;
        red[0][e] = red[0][e] + red[1][e] + red[2][e] + red[3][e];
      }
      __syncthreads();
      unsigned short* hout = h1r + (size_t)(t & (R_ - 1)) * (B_ * H_);
#pragma unroll
      for (int it = 0; it < 2; ++it) {
        float zi = red[0][ridx[it] + 0] + bz[it][0];
        float zj = red[0][ridx[it] + 1] + bz[it][1];
        float zf = red[0][ridx[it] + 2] + bz[it][2];
        float zo = red[0][ridx[it] + 3] + bz[it][3];
        float cn = creg[it] * sigm(zf + 1.0f) + sigm(zi) * tanh_(zj);
        float hn = tanh_(cn) * sigm(zo);
        creg[it] = cn;
        st_bypass_short(hout + hoff[it], (unsigned int)f2bf(hn));
      }
      asm volatile("s_waitcnt vmcnt(0)" ::: "memory");  // h1(t) at L3
      __syncthreads();                                  // all threads drained
      if (tid == 0) st_flag(f1 + bid, t + 1);           // single-writer publish
    }
  } else {
    // ----- layer-2 role: K = 2048, 16 chunks/wave; weights -> 128 VGPR -----
    const int kcbase = wid * 16;
    s8 bw[16][2];
#pragma unroll
    for (int c = 0; c < 16; ++c) {
      int kk = (kcbase + c) * 32 + kseg;
      bw[c][0] = *(const s8*)(W2p + (size_t)bcol[0] * K2_ + kk);
      bw[c][1] = *(const s8*)(W2p + (size_t)bcol[1] * K2_ + kk);
    }
#pragma unroll
    for (int c = 0; c < 16; ++c)
      asm volatile("" : "+v"(bw[c][0]), "+v"(bw[c][1]));   // pin in regs

    for (int t = 0; t < T_; ++t) {
      // per-wave selective waits: waves 0-1 read h1(t); waves 2-3 read h2(t-1)
      if (wid < 2) wave_wait1(f1 + lane4, t + 1);
      else         wave_wait1(f2 + lane4, t);
      if ((t & (R_ - 1)) == 0 && t)
        __builtin_amdgcn_fence(__ATOMIC_ACQUIRE, "agent");

      const unsigned short* hsrc = h1r + (size_t)(t & (R_ - 1)) * (B_ * H_);
      const unsigned short* h2prev = h2all + (size_t)t * (B_ * H_);
      f32x4 acc[4][2];
#pragma unroll
      for (int i = 0; i < 4; ++i)
#pragma unroll
        for (int j = 0; j < 2; ++j) acc[i][j] = (f32x4){0.f, 0.f, 0.f, 0.f};
      s8 a[4], an[4];
      auto LD = [&](int kc, s8* A) {
        int kk = kc * 32 + kseg;
        if (kk < H_) {
#pragma unroll
          for (int i = 0; i < 4; ++i) A[i] = *(const s8*)(hsrc + (size_t)arow[i] * H_ + kk);
        } else {
#pragma unroll
          for (int i = 0; i < 4; ++i) A[i] = *(const s8*)(h2prev + (size_t)arow[i] * H_ + (kk - H_));
        }
      };
      LD(kcbase, a);
#pragma unroll
      for (int c = 0; c < 16; ++c) {
        if (c + 1 < 16) LD(kcbase + c + 1, an);
#pragma unroll
        for (int i = 0; i < 4; ++i)
#pragma unroll
          for (int j = 0; j < 2; ++j) acc[i][j] = mfma16(a[i], bw[c][j], acc[i][j]);
#pragma unroll
        for (int i = 0; i < 4; ++i) a[i] = an[i];
      }
#pragma unroll
      for (int i = 0; i < 4; ++i)
#pragma unroll
        for (int j = 0; j < 2; ++j)
#pragma unroll
          for (int r = 0; r < 4; ++r)
            red[wid][(i * 16 + quad * 4 + r) * 32 + (j * 16 + l15)] = acc[i][j][r];
      __syncthreads();
#pragma unroll
      for (int it = 0; it < 8; ++it) {
        int e = it * 256 + tid;
        red[0][e] = red[0][e] + red[1][e] + red[2][e] + red[3][e];
      }
      __syncthreads();
      unsigned short* hout = h2all + (size_t)(t + 1) * (B_ * H_);
#pragma unroll
      for (int it = 0; it < 2; ++it) {
        float zi = red[0][ridx[it] + 0] + bz[it][0];
        float zj = red[0][ridx[it] + 1] + bz[it][1];
        float zf = red[0][ridx[it] + 2] + bz[it][2];
        float zo = red[0][ridx[it] + 3] + bz[it][3];
        float cn = creg[it] * sigm(zf + 1.0f) + sigm(zi) * tanh_(zj);
        float hn = tanh_(cn) * sigm(zo);
        creg[it] = cn;
        st_bypass_short(hout + hoff[it], (unsigned int)f2bf(hn));
      }
      asm volatile("s_waitcnt vmcnt(0)" ::: "memory");
      __syncthreads();
      if (tid == 0) st_flag(f2 + bid - 256, t + 1);     // single-writer publish
    }
  }
}

// ---------------------------------------------------------------------------
// Tail: logits = h2 @ outW + outB, dual softmax, probs out, CE loss.
// ---------------------------------------------------------------------------
__global__ __launch_bounds__(256, 1) void proj_kernel(
    const unsigned short* __restrict__ h2flat,
    const unsigned short* __restrict__ outWp,
    const float* __restrict__ outB,
    const int* __restrict__ targets,
    float* __restrict__ out,
    float* __restrict__ loss)
{
  __shared__ float lg[128][129];
  __shared__ float red2[256];
  const int r0 = blockIdx.x * 128;
  const int tid = threadIdx.x;
  const int wid = tid >> 6, lane = tid & 63;
  const int quad = lane >> 4, l15 = lane & 15;
  const int wr = (wid & 1) * 64, wc = (wid >> 1) * 64;
  const int kseg = quad * 8;

  f32x4 acc[4][4];
#pragma unroll
  for (int i = 0; i < 4; ++i)
#pragma unroll
    for (int j = 0; j < 4; ++j) acc[i][j] = (f32x4){0.f, 0.f, 0.f, 0.f};

  int arow[4], bcolv[4];
#pragma unroll
  for (int i = 0; i < 4; ++i) arow[i] = r0 + wr + i * 16 + l15;
#pragma unroll
  for (int j = 0; j < 4; ++j) bcolv[j] = wc + j * 16 + l15;

  s8 a[4], b[4], an[4], bn[4];
  auto LD = [&](int kc, s8* A, s8* Bv) {
    int kk = kc * 32 + kseg;
#pragma unroll
    for (int i = 0; i < 4; ++i) A[i] = *(const s8*)(h2flat + (size_t)arow[i] * H_ + kk);
#pragma unroll
    for (int j = 0; j < 4; ++j) Bv[j] = *(const s8*)(outWp + (size_t)bcolv[j] * H_ + kk);
  };
  LD(0, a, b);
  for (int c = 0; c < 32; ++c) {
    if (c + 1 < 32) LD(c + 1, an, bn);
#pragma unroll
    for (int i = 0; i < 4; ++i)
#pragma unroll
      for (int j = 0; j < 4; ++j) acc[i][j] = mfma16(a[i], b[j], acc[i][j]);
#pragma unroll
    for (int i = 0; i < 4; ++i) a[i] = an[i];
#pragma unroll
    for (int j = 0; j < 4; ++j) b[j] = bn[j];
  }

#pragma unroll
  for (int i = 0; i < 4; ++i)
#pragma unroll
    for (int j = 0; j < 4; ++j)
#pragma unroll
      for (int r = 0; r < 4; ++r)
        lg[wr + i * 16 + quad * 4 + r][wc + j * 16 + l15] = acc[i][j][r] + outB[bcolv[j]];
  __syncthreads();

  const int row = tid >> 1, half = tid & 1;
  const int cbeg = half ? 48 : 0, cend = half ? 128 : 48;
  float m = -1e30f;
  for (int c = cbeg; c < cend; ++c) m = fmaxf(m, lg[row][c]);
  float s = 0.f;
  for (int c = cbeg; c < cend; ++c) s += __expf(lg[row][c] - m);
  float rinv = 1.f / s;
  float* orow = out + (size_t)(r0 + row) * D_;
  for (int c = cbeg; c < cend; ++c) orow[c] = __expf(lg[row][c] - m) * rinv;

  int tg = targets[(size_t)(r0 + row) * 2 + half];
  int tc = half ? (48 + tg) : tg;
  float ce = -(lg[row][tc] - m - logf(s));
  red2[tid] = 0.5f * ce;
  __syncthreads();
  for (int o = 128; o > 0; o >>= 1) {
    if (tid < o) red2[tid] += red2[tid + o];
    __syncthreads();
  }
  if (tid == 0) atomicAdd(loss, red2[0]);
}

__global__ void finalize_loss(const float* __restrict__ loss, float* __restrict__ out)
{
  out[(size_t)T_ * B_ * D_] = loss[0] * (1.f / (float)(T_ * B_));
}

// ---------------------------------------------------------------------------
extern "C" void kernel_launch(void* const* d_in, const int* in_sizes, int n_in,
                              void* d_out, int out_size, void* d_ws, size_t ws_size,
                              hipStream_t stream)
{
  const float* inSeq = (const float*)d_in[0];
  const int* targets = (const int*)d_in[1];
  const float* W1 = (const float*)d_in[2];
  const float* b1 = (const float*)d_in[3];
  const float* W2 = (const float*)d_in[4];
  const float* b2 = (const float*)d_in[5];
  const float* outW = (const float*)d_in[6];
  const float* outB = (const float*)d_in[7];
  float* out = (float*)d_out;

  // workspace layout: fallback-needed arrays first (~104 MB), then the
  // persistent-only extras (flags + h1 ring) -> ~112 MB total.
  char* w = (char*)d_ws;
  auto alloc = [&](size_t bytes) {
    char* r = w;
    w += (bytes + 255) & ~(size_t)255;
    return r;
  };
  unsigned short* W1p = (unsigned short*)alloc((size_t)4096 * K1_ * 2);
  unsigned short* W2p = (unsigned short*)alloc((size_t)4096 * K2_ * 2);
  unsigned short* xbf = (unsigned short*)alloc((size_t)T_ * B_ * D_ * 2);
  unsigned short* h1b = (unsigned short*)alloc((size_t)2 * B_ * H_ * 2);
  unsigned short* h2all = (unsigned short*)alloc((size_t)(T_ + 1) * B_ * H_ * 2);
  float* c1 = (float*)alloc((size_t)B_ * H_ * 4);
  float* c2 = (float*)alloc((size_t)B_ * H_ * 4);
  unsigned short* outWp = (unsigned short*)alloc((size_t)H_ * D_ * 2);
  float* loss = (float*)alloc(256);
  int* f1 = (int*)alloc(256 * 4);
  int* f2 = (int*)alloc(256 * 4);
  unsigned short* h1r = (unsigned short*)alloc((size_t)R_ * B_ * H_ * 2);

  const bool fits = ((size_t)(w - (char*)d_ws) <= ws_size);
  if (!fits) { f1 = nullptr; f2 = nullptr; h1r = nullptr; }

  prep_misc<<<dim3((T_ * B_ * D_) / 256), dim3(256), 0, stream>>>(
      inSeq, outW, xbf, outWp, h1b, h1r, h2all, c1, c2, loss, f1, f2);
  pack_w<<<dim3(K1_ / 64, 16, 4), dim3(256), 0, stream>>>(W1, W1p, K1_);
  pack_w<<<dim3(K2_ / 64, 16, 4), dim3(256), 0, stream>>>(W2, W2p, K2_);

  hipError_t ce = hipErrorUnknown;
  if (fits) {
    void* kargs[] = {(void*)&xbf, (void*)&W1p, (void*)&W2p, (void*)&b1,
                     (void*)&b2,  (void*)&h1r, (void*)&h2all,
                     (void*)&f1,  (void*)&f2};
    ce = hipLaunchCooperativeKernel((const void*)lstm_persistent,
                                    dim3(512), dim3(256), kargs, 0, stream);
  }
  if (ce != hipSuccess) {
    // Fallback: verified per-phase launch loop.
    (void)hipGetLastError();
    for (int p = 0; p <= T_; ++p)
      phase_kernel<<<dim3(512), dim3(256), 0, stream>>>(
          p, xbf, W1p, W2p, b1, b2, h1b, h2all, c1, c2);
  }

  proj_kernel<<<dim3(256), dim3(256), 0, stream>>>(
      h2all + (size_t)B_ * H_, outWp, outB, targets, out, loss);
  finalize_loss<<<dim3(1), dim3(1), 0, stream>>>(loss, out);
}

// Round 9
// 5097.807 us; speedup vs baseline: 1.1394x; 1.0820x over previous
//
#include <hip/hip_runtime.h>
#include <cstdint>
#include <cstddef>

// Model dims
#define T_ 256
#define B_ 128
#define D_ 128
#define H_ 1024
#define K1_ 1152   // D + H
#define K2_ 2048   // 2H

// h1 ring: 32 write-once-per-window slots; agent-acquire fence every R_ steps
#define R_ 32

typedef __bf16 bf16x8 __attribute__((ext_vector_type(8)));
typedef short s8 __attribute__((ext_vector_type(8)));
typedef float f32x4 __attribute__((ext_vector_type(4)));

__device__ __forceinline__ unsigned short f2bf(float f) {
  unsigned int u = __builtin_bit_cast(unsigned int, f);
  u += 0x7fff + ((u >> 16) & 1);   // RNE
  return (unsigned short)(u >> 16);
}
__device__ __forceinline__ float sigm(float x) { return 1.f / (1.f + __expf(-x)); }
__device__ __forceinline__ float tanh_(float x) { return 1.f - 2.f / (__expf(2.f * x) + 1.f); }

__device__ __forceinline__ f32x4 mfma16(s8 a, s8 b, f32x4 c) {
  return __builtin_amdgcn_mfma_f32_16x16x32_bf16(
      __builtin_bit_cast(bf16x8, a), __builtin_bit_cast(bf16x8, b), c, 0, 0, 0);
}

// Write-through 2B store to the coherence point (L3): producers publish h.
__device__ __forceinline__ void st_bypass_short(unsigned short* p, unsigned int v) {
  asm volatile("global_store_short %0, %1, off sc0 sc1" :: "v"(p), "v"(v) : "memory");
}
// Single-writer flag publish (plain dword, write-through).
__device__ __forceinline__ void st_flag(int* p, int v) {
  asm volatile("global_store_dword %0, %1, off sc0 sc1" :: "v"(p), "v"(v) : "memory");
}

// Wave-parallel wait (called by ONE wave per block): 64 lanes each watch 4
// flags (dwordx4 bypass covers the 256-entry array); done when ALL >= want.
// s_sleep(3) backoff keeps flag-poll traffic off the L3 critical path.
__device__ __forceinline__ void wave_wait1(const int* p, int want) {
  for (;;) {
    int4 v;
    asm volatile("global_load_dwordx4 %0, %1, off sc0 sc1\n\ts_waitcnt vmcnt(0)"
                 : "=v"(v) : "v"(p) : "memory");
    int ok = (v.x >= want) && (v.y >= want) && (v.z >= want) && (v.w >= want);
    if (__all(ok)) break;
    __builtin_amdgcn_s_sleep(3);
  }
}
__device__ __forceinline__ void wave_wait2(const int* pa, int wa,
                                           const int* pb, int wb) {
  for (;;) {
    int4 a, b;
    asm volatile("global_load_dwordx4 %0, %2, off sc0 sc1\n\t"
                 "global_load_dwordx4 %1, %3, off sc0 sc1\n\t"
                 "s_waitcnt vmcnt(0)"
                 : "=v"(a), "=v"(b) : "v"(pa), "v"(pb) : "memory");
    int ok = (a.x >= wa) && (a.y >= wa) && (a.z >= wa) && (a.w >= wa) &&
             (b.x >= wb) && (b.y >= wb) && (b.z >= wb) && (b.w >= wb);
    if (__all(ok)) break;
    __builtin_amdgcn_s_sleep(3);
  }
}

// ---------------------------------------------------------------------------
// Prep: convert inSeq -> bf16, pack outW -> [col][k] bf16, zero states/loss,
// zero flags, zero ring slot R_-1 (h1(t=-1)).
// ---------------------------------------------------------------------------
__global__ void prep_misc(const float* __restrict__ inSeq,
                          const float* __restrict__ outW,
                          unsigned short* __restrict__ xbf,
                          unsigned short* __restrict__ outWp,
                          unsigned short* __restrict__ h1b,
                          unsigned short* __restrict__ h1r,
                          unsigned short* __restrict__ h2all,
                          float* __restrict__ c1, float* __restrict__ c2,
                          float* __restrict__ loss,
                          int* __restrict__ f1, int* __restrict__ f2)
{
  int i = blockIdx.x * 256 + threadIdx.x;
  if (i < T_ * B_ * D_) xbf[i] = f2bf(inSeq[i]);
  if (i < B_ * H_) {
    c1[i] = 0.f; c2[i] = 0.f;
    h1b[B_ * H_ + i] = 0;                       // fallback parity-1 buffer
    if (h1r) h1r[(size_t)(R_ - 1) * B_ * H_ + i] = 0;  // ring slot for h1(-1)
    h2all[i] = 0;                               // slot 0 = h2(t=-1)
  }
  if (i < H_ * D_) {          // outWp[c][k] = outW[k][c]
    int c = i >> 10, k = i & 1023;
    outWp[i] = f2bf(outW[(size_t)k * D_ + c]);
  }
  if (f1 && i < 256) { f1[i] = 0; f2[i] = 0; }
  if (i == 0) loss[0] = 0.f;
}

// ---------------------------------------------------------------------------
// Pack LSTM weights: src fp32 [K][4096] (gate-major cols: i|j|f|o blocks of H)
//   -> dst bf16 [4096][K], dst row = 4*j + g  (gate-interleaved, k-major)
// ---------------------------------------------------------------------------
__global__ void pack_w(const float* __restrict__ src, unsigned short* __restrict__ dst, int K)
{
  __shared__ float tile[64][65];
  int k0 = blockIdx.x * 64, j0 = blockIdx.y * 64, g = blockIdx.z;
  int tid = threadIdx.x;
#pragma unroll
  for (int e = 0; e < 16; ++e) {
    int li = e * 256 + tid;
    int kl = li >> 6, jl = li & 63;
    tile[kl][jl] = src[(size_t)(k0 + kl) * 4096 + g * 1024 + j0 + jl];
  }
  __syncthreads();
#pragma unroll
  for (int e = 0; e < 16; ++e) {
    int li = e * 256 + tid;
    int jl = li >> 6, kl = li & 63;
    dst[(size_t)((j0 + jl) * 4 + g) * K + k0 + kl] = f2bf(tile[kl][jl]);
  }
}

// ---------------------------------------------------------------------------
// FALLBACK path (identical to verified kernel): per-phase launches.
// ---------------------------------------------------------------------------
__global__ __launch_bounds__(256, 2) void phase_kernel(
    int p,
    const unsigned short* __restrict__ xbf,
    const unsigned short* __restrict__ W1p,
    const unsigned short* __restrict__ W2p,
    const float* __restrict__ b1,
    const float* __restrict__ b2,
    unsigned short* __restrict__ h1b,
    unsigned short* __restrict__ h2all,
    float* __restrict__ c1,
    float* __restrict__ c2)
{
  __shared__ float red[4][2048];
  const int bid = blockIdx.x;
  const bool isL2 = bid >= 256;
  if (!isL2 && p >= T_) return;
  if (isL2 && p == 0) return;
  const int jb = isL2 ? (bid - 256) : bid;
  const int mt = jb & 1, nt = jb >> 1;
  const int t = isL2 ? (p - 1) : p;
  const int r0 = mt * 64, c0 = nt * 32;
  const int tid = threadIdx.x;
  const int wid = tid >> 6, lane = tid & 63;
  const int quad = lane >> 4, l15 = lane & 15;
  const int kseg = quad * 8;

  const unsigned short* hsrc = h1b + (size_t)((p + 1) & 1) * (B_ * H_);

  f32x4 acc[4][2];
#pragma unroll
  for (int i = 0; i < 4; ++i)
#pragma unroll
    for (int j = 0; j < 2; ++j) acc[i][j] = (f32x4){0.f, 0.f, 0.f, 0.f};

  int arow[4], bcol[2];
#pragma unroll
  for (int i = 0; i < 4; ++i) arow[i] = r0 + i * 16 + l15;
#pragma unroll
  for (int j = 0; j < 2; ++j) bcol[j] = c0 + j * 16 + l15;

  if (!isL2) {
    const unsigned short* xt = xbf + (size_t)t * (B_ * D_);
    const int cpw = 9;
    const int kcbase = wid * cpw;
    s8 a[4], b[2], an[4], bn[2];
    auto LD = [&](int kc, s8* A, s8* Bv) {
      int kk = kc * 32 + kseg;
      if (kk < D_) {
#pragma unroll
        for (int i = 0; i < 4; ++i) A[i] = *(const s8*)(xt + (size_t)arow[i] * D_ + kk);
      } else {
#pragma unroll
        for (int i = 0; i < 4; ++i) A[i] = *(const s8*)(hsrc + (size_t)arow[i] * H_ + (kk - D_));
      }
#pragma unroll
      for (int j = 0; j < 2; ++j) Bv[j] = *(const s8*)(W1p + (size_t)bcol[j] * K1_ + kk);
    };
    LD(kcbase, a, b);
    for (int c = 0; c < cpw; ++c) {
      if (c + 1 < cpw) LD(kcbase + c + 1, an, bn);
#pragma unroll
      for (int i = 0; i < 4; ++i)
#pragma unroll
        for (int j = 0; j < 2; ++j) acc[i][j] = mfma16(a[i], b[j], acc[i][j]);
#pragma unroll
      for (int i = 0; i < 4; ++i) a[i] = an[i];
      b[0] = bn[0]; b[1] = bn[1];
    }
  } else {
    const unsigned short* h2prev = h2all + (size_t)t * (B_ * H_);
    const int cpw = 16;
    const int kcbase = wid * cpw;
    s8 a[4], b[2], an[4], bn[2];
    auto LD = [&](int kc, s8* A, s8* Bv) {
      int kk = kc * 32 + kseg;
      if (kk < H_) {
#pragma unroll
        for (int i = 0; i < 4; ++i) A[i] = *(const s8*)(hsrc + (size_t)arow[i] * H_ + kk);
      } else {
#pragma unroll
        for (int i = 0; i < 4; ++i) A[i] = *(const s8*)(h2prev + (size_t)arow[i] * H_ + (kk - H_));
      }
#pragma unroll
      for (int j = 0; j < 2; ++j) Bv[j] = *(const s8*)(W2p + (size_t)bcol[j] * K2_ + kk);
    };
    LD(kcbase, a, b);
    for (int c = 0; c < cpw; ++c) {
      if (c + 1 < cpw) LD(kcbase + c + 1, an, bn);
#pragma unroll
      for (int i = 0; i < 4; ++i)
#pragma unroll
        for (int j = 0; j < 2; ++j) acc[i][j] = mfma16(a[i], b[j], acc[i][j]);
#pragma unroll
      for (int i = 0; i < 4; ++i) a[i] = an[i];
      b[0] = bn[0]; b[1] = bn[1];
    }
  }

#pragma unroll
  for (int i = 0; i < 4; ++i)
#pragma unroll
    for (int j = 0; j < 2; ++j)
#pragma unroll
      for (int r = 0; r < 4; ++r)
        red[wid][(i * 16 + quad * 4 + r) * 32 + (j * 16 + l15)] = acc[i][j][r];
  __syncthreads();
#pragma unroll
  for (int it = 0; it < 8; ++it) {
    int e = it * 256 + tid;
    red[0][e] = red[0][e] + red[1][e] + red[2][e] + red[3][e];
  }
  __syncthreads();

  const float* bias = isL2 ? b2 : b1;
  float* cst = isL2 ? c2 : c1;
  unsigned short* hout = isL2 ? (h2all + (size_t)(t + 1) * (B_ * H_))
                              : (h1b + (size_t)(p & 1) * (B_ * H_));
#pragma unroll
  for (int it = 0; it < 2; ++it) {
    int s = it * 256 + tid;
    int row = s >> 3, u = s & 7;
    int jg = (c0 >> 2) + u;
    float zi = red[0][row * 32 + u * 4 + 0] + bias[0 * H_ + jg];
    float zj = red[0][row * 32 + u * 4 + 1] + bias[1 * H_ + jg];
    float zf = red[0][row * 32 + u * 4 + 2] + bias[2 * H_ + jg];
    float zo = red[0][row * 32 + u * 4 + 3] + bias[3 * H_ + jg];
    int rg = r0 + row;
    float co = cst[(size_t)rg * H_ + jg];
    float cn = co * sigm(zf + 1.0f) + sigm(zi) * tanh_(zj);
    float hn = tanh_(cn) * sigm(zo);
    cst[(size_t)rg * H_ + jg] = cn;
    hout[(size_t)rg * H_ + jg] = f2bf(hn);
  }
}

// ---------------------------------------------------------------------------
// PERSISTENT kernel (round-8 structure; POLL-STORM FIX):
//  Rounds 4-8 had ALL 2048 waves spinning on sc0/sc1 full-array flag loads
//  (~10 TB/s of uncacheable traffic into 16 L3 lines) — saturating the
//  coherence point that every h-load/store also crosses. Now exactly ONE
//  wave per block polls (dwordx4/lane covers the array in one instruction,
//  s_sleep(3) backoff), then __syncthreads() releases the block. L1's
//  ring-WAR f2 check runs once per 16 steps (f2 >= t-16 at t%16==0, which
//  dominates the per-step f2 >= t-31 requirement).
//  All data movement identical to rounds 5/8 (write-through h publishes,
//  plain cached consumer loads, 32-slot ring + 1 acquire fence / 32 steps).
// ---------------------------------------------------------------------------
__global__ __attribute__((amdgpu_waves_per_eu(2, 2))) __launch_bounds__(256)
void lstm_persistent(
    const unsigned short* __restrict__ xbf,
    const unsigned short* __restrict__ W1p,
    const unsigned short* __restrict__ W2p,
    const float* __restrict__ b1,
    const float* __restrict__ b2,
    unsigned short* __restrict__ h1r,
    unsigned short* __restrict__ h2all,
    int* __restrict__ f1,
    int* __restrict__ f2)
{
  __shared__ float red[4][2048];
  const int bid = blockIdx.x;
  const bool isL2 = bid >= 256;
  const int jb = isL2 ? (bid - 256) : bid;
  const int mt = jb & 1, nt = jb >> 1;
  const int r0 = mt * 64, c0 = nt * 32;
  const int tid = threadIdx.x;
  const int wid = tid >> 6, lane = tid & 63;
  const int quad = lane >> 4, l15 = lane & 15;
  const int kseg = quad * 8;
  const int lane4 = lane * 4;

  int arow[4], bcol[2];
#pragma unroll
  for (int i = 0; i < 4; ++i) arow[i] = r0 + i * 16 + l15;
#pragma unroll
  for (int j = 0; j < 2; ++j) bcol[j] = c0 + j * 16 + l15;

  // Register-resident epilogue state (fixed (row,unit) per thread).
  const float* bias = isL2 ? b2 : b1;
  int ridx[2];
  unsigned hoff[2];
  float bz[2][4], creg[2];
#pragma unroll
  for (int it = 0; it < 2; ++it) {
    int s = it * 256 + tid;
    int row = s >> 3, u = s & 7;
    int jg = (c0 >> 2) + u;
    ridx[it] = row * 32 + u * 4;
    hoff[it] = (unsigned)((r0 + row) * H_ + jg);
#pragma unroll
    for (int g = 0; g < 4; ++g) bz[it][g] = bias[g * H_ + jg];
    creg[it] = 0.f;
  }

  if (!isL2) {
    // ----- layer-1 role: K = 1152, 9 chunks/wave -----
    const int kcbase = wid * 9;
    s8 bw[9][2];
#pragma unroll
    for (int c = 0; c < 9; ++c) {
      int kk = (kcbase + c) * 32 + kseg;
      bw[c][0] = *(const s8*)(W1p + (size_t)bcol[0] * K1_ + kk);
      bw[c][1] = *(const s8*)(W1p + (size_t)bcol[1] * K1_ + kk);
    }
#pragma unroll
    for (int c = 0; c < 9; ++c)
      asm volatile("" : "+v"(bw[c][0]), "+v"(bw[c][1]));   // pin in regs

    for (int t = 0; t < T_; ++t) {
      // single polling wave; others wait at the barrier
      if (wid == 0) {
        if ((t & 15) == 0) wave_wait2(f1 + lane4, t, f2 + lane4, t - 16);
        else               wave_wait1(f1 + lane4, t);
      }
      __syncthreads();
      if ((t & (R_ - 1)) == 0 && t)
        __builtin_amdgcn_fence(__ATOMIC_ACQUIRE, "agent"); // flush >=R_-old lines

      const unsigned short* hsrc = h1r + (size_t)((t + R_ - 1) & (R_ - 1)) * (B_ * H_);
      const unsigned short* xt = xbf + (size_t)t * (B_ * D_);
      f32x4 acc[4][2];
#pragma unroll
      for (int i = 0; i < 4; ++i)
#pragma unroll
        for (int j = 0; j < 2; ++j) acc[i][j] = (f32x4){0.f, 0.f, 0.f, 0.f};
      s8 a[4], an[4];
      auto LD = [&](int kc, s8* A) {
        int kk = kc * 32 + kseg;
        if (kk < D_) {
#pragma unroll
          for (int i = 0; i < 4; ++i) A[i] = *(const s8*)(xt + (size_t)arow[i] * D_ + kk);
        } else {
#pragma unroll
          for (int i = 0; i < 4; ++i) A[i] = *(const s8*)(hsrc + (size_t)arow[i] * H_ + (kk - D_));
        }
      };
      LD(kcbase, a);
#pragma unroll
      for (int c = 0; c < 9; ++c) {
        if (c + 1 < 9) LD(kcbase + c + 1, an);
#pragma unroll
        for (int i = 0; i < 4; ++i)
#pragma unroll
          for (int j = 0; j < 2; ++j) acc[i][j] = mfma16(a[i], bw[c][j], acc[i][j]);
#pragma unroll
        for (int i = 0; i < 4; ++i) a[i] = an[i];
      }
#pragma unroll
      for (int i = 0; i < 4; ++i)
#pragma unroll
        for (int j = 0; j < 2; ++j)
#pragma unroll
          for (int r = 0; r < 4; ++r)
            red[wid][(i * 16 + quad * 4 + r) * 32 + (j * 16 + l15)] = acc[i][j][r];
      __syncthreads();
#pragma unroll
      for (int it = 0; it < 8; ++it) {
        int e = it * 256 + tid;
        red[0][e] = red[0][e] + red[1][e] + red[2][e] + red[3][e];
      }
      __syncthreads();
      unsigned short* hout = h1r + (size_t)(t & (R_ - 1)) * (B_ * H_);
#pragma unroll
      for (int it = 0; it < 2; ++it) {
        float zi = red[0][ridx[it] + 0] + bz[it][0];
        float zj = red[0][ridx[it] + 1] + bz[it][1];
        float zf = red[0][ridx[it] + 2] + bz[it][2];
        float zo = red[0][ridx[it] + 3] + bz[it][3];
        float cn = creg[it] * sigm(zf + 1.0f) + sigm(zi) * tanh_(zj);
        float hn = tanh_(cn) * sigm(zo);
        creg[it] = cn;
        st_bypass_short(hout + hoff[it], (unsigned int)f2bf(hn));
      }
      asm volatile("s_waitcnt vmcnt(0)" ::: "memory");  // h1(t) at L3
      __syncthreads();                                  // all threads drained
      if (tid == 0) st_flag(f1 + jb, t + 1);            // single-writer publish
    }
  } else {
    // ----- layer-2 role: K = 2048, 16 chunks/wave -----
    const int kcbase = wid * 16;
    s8 bw[16][2];
#pragma unroll
    for (int c = 0; c < 16; ++c) {
      int kk = (kcbase + c) * 32 + kseg;
      bw[c][0] = *(const s8*)(W2p + (size_t)bcol[0] * K2_ + kk);
      bw[c][1] = *(const s8*)(W2p + (size_t)bcol[1] * K2_ + kk);
    }
#pragma unroll
    for (int c = 0; c < 16; ++c)
      asm volatile("" : "+v"(bw[c][0]), "+v"(bw[c][1]));   // pin in regs

    for (int t = 0; t < T_; ++t) {
      // single polling wave: needs h1(t) complete AND h2(t-1) complete
      if (wid == 0) wave_wait2(f1 + lane4, t + 1, f2 + lane4, t);
      __syncthreads();
      if ((t & (R_ - 1)) == 0 && t)
        __builtin_amdgcn_fence(__ATOMIC_ACQUIRE, "agent");

      const unsigned short* hsrc = h1r + (size_t)(t & (R_ - 1)) * (B_ * H_);
      const unsigned short* h2prev = h2all + (size_t)t * (B_ * H_);
      f32x4 acc[4][2];
#pragma unroll
      for (int i = 0; i < 4; ++i)
#pragma unroll
        for (int j = 0; j < 2; ++j) acc[i][j] = (f32x4){0.f, 0.f, 0.f, 0.f};
      s8 a[4], an[4];
      auto LD = [&](int kc, s8* A) {
        int kk = kc * 32 + kseg;
        if (kk < H_) {
#pragma unroll
          for (int i = 0; i < 4; ++i) A[i] = *(const s8*)(hsrc + (size_t)arow[i] * H_ + kk);
        } else {
#pragma unroll
          for (int i = 0; i < 4; ++i) A[i] = *(const s8*)(h2prev + (size_t)arow[i] * H_ + (kk - H_));
        }
      };
      LD(kcbase, a);
#pragma unroll
      for (int c = 0; c < 16; ++c) {
        if (c + 1 < 16) LD(kcbase + c + 1, an);
#pragma unroll
        for (int i = 0; i < 4; ++i)
#pragma unroll
          for (int j = 0; j < 2; ++j) acc[i][j] = mfma16(a[i], bw[c][j], acc[i][j]);
#pragma unroll
        for (int i = 0; i < 4; ++i) a[i] = an[i];
      }
#pragma unroll
      for (int i = 0; i < 4; ++i)
#pragma unroll
        for (int j = 0; j < 2; ++j)
#pragma unroll
          for (int r = 0; r < 4; ++r)
            red[wid][(i * 16 + quad * 4 + r) * 32 + (j * 16 + l15)] = acc[i][j][r];
      __syncthreads();
#pragma unroll
      for (int it = 0; it < 8; ++it) {
        int e = it * 256 + tid;
        red[0][e] = red[0][e] + red[1][e] + red[2][e] + red[3][e];
      }
      __syncthreads();
      unsigned short* hout = h2all + (size_t)(t + 1) * (B_ * H_);
#pragma unroll
      for (int it = 0; it < 2; ++it) {
        float zi = red[0][ridx[it] + 0] + bz[it][0];
        float zj = red[0][ridx[it] + 1] + bz[it][1];
        float zf = red[0][ridx[it] + 2] + bz[it][2];
        float zo = red[0][ridx[it] + 3] + bz[it][3];
        float cn = creg[it] * sigm(zf + 1.0f) + sigm(zi) * tanh_(zj);
        float hn = tanh_(cn) * sigm(zo);
        creg[it] = cn;
        st_bypass_short(hout + hoff[it], (unsigned int)f2bf(hn));
      }
      asm volatile("s_waitcnt vmcnt(0)" ::: "memory");
      __syncthreads();
      if (tid == 0) st_flag(f2 + jb, t + 1);            // single-writer publish
    }
  }
}

// ---------------------------------------------------------------------------
// Tail: logits = h2 @ outW + outB, dual softmax, probs out, CE loss.
// ---------------------------------------------------------------------------
__global__ __launch_bounds__(256, 1) void proj_kernel(
    const unsigned short* __restrict__ h2flat,
    const unsigned short* __restrict__ outWp,
    const float* __restrict__ outB,
    const int* __restrict__ targets,
    float* __restrict__ out,
    float* __restrict__ loss)
{
  __shared__ float lg[128][129];
  __shared__ float red2[256];
  const int r0 = blockIdx.x * 128;
  const int tid = threadIdx.x;
  const int wid = tid >> 6, lane = tid & 63;
  const int quad = lane >> 4, l15 = lane & 15;
  const int wr = (wid & 1) * 64, wc = (wid >> 1) * 64;
  const int kseg = quad * 8;

  f32x4 acc[4][4];
#pragma unroll
  for (int i = 0; i < 4; ++i)
#pragma unroll
    for (int j = 0; j < 4; ++j) acc[i][j] = (f32x4){0.f, 0.f, 0.f, 0.f};

  int arow[4], bcolv[4];
#pragma unroll
  for (int i = 0; i < 4; ++i) arow[i] = r0 + wr + i * 16 + l15;
#pragma unroll
  for (int j = 0; j < 4; ++j) bcolv[j] = wc + j * 16 + l15;

  s8 a[4], b[4], an[4], bn[4];
  auto LD = [&](int kc, s8* A, s8* Bv) {
    int kk = kc * 32 + kseg;
#pragma unroll
    for (int i = 0; i < 4; ++i) A[i] = *(const s8*)(h2flat + (size_t)arow[i] * H_ + kk);
#pragma unroll
    for (int j = 0; j < 4; ++j) Bv[j] = *(const s8*)(outWp + (size_t)bcolv[j] * H_ + kk);
  };
  LD(0, a, b);
  for (int c = 0; c < 32; ++c) {
    if (c + 1 < 32) LD(c + 1, an, bn);
#pragma unroll
    for (int i = 0; i < 4; ++i)
#pragma unroll
      for (int j = 0; j < 4; ++j) acc[i][j] = mfma16(a[i], b[j], acc[i][j]);
#pragma unroll
    for (int i = 0; i < 4; ++i) a[i] = an[i];
#pragma unroll
    for (int j = 0; j < 4; ++j) b[j] = bn[j];
  }

#pragma unroll
  for (int i = 0; i < 4; ++i)
#pragma unroll
    for (int j = 0; j < 4; ++j)
#pragma unroll
      for (int r = 0; r < 4; ++r)
        lg[wr + i * 16 + quad * 4 + r][wc + j * 16 + l15] = acc[i][j][r] + outB[bcolv[j]];
  __syncthreads();

  const int row = tid >> 1, half = tid & 1;
  const int cbeg = half ? 48 : 0, cend = half ? 128 : 48;
  float m = -1e30f;
  for (int c = cbeg; c < cend; ++c) m = fmaxf(m, lg[row][c]);
  float s = 0.f;
  for (int c = cbeg; c < cend; ++c) s += __expf(lg[row][c] - m);
  float rinv = 1.f / s;
  float* orow = out + (size_t)(r0 + row) * D_;
  for (int c = cbeg; c < cend; ++c) orow[c] = __expf(lg[row][c] - m) * rinv;

  int tg = targets[(size_t)(r0 + row) * 2 + half];
  int tc = half ? (48 + tg) : tg;
  float ce = -(lg[row][tc] - m - logf(s));
  red2[tid] = 0.5f * ce;
  __syncthreads();
  for (int o = 128; o > 0; o >>= 1) {
    if (tid < o) red2[tid] += red2[tid + o];
    __syncthreads();
  }
  if (tid == 0) atomicAdd(loss, red2[0]);
}

__global__ void finalize_loss(const float* __restrict__ loss, float* __restrict__ out)
{
  out[(size_t)T_ * B_ * D_] = loss[0] * (1.f / (float)(T_ * B_));
}

// ---------------------------------------------------------------------------
extern "C" void kernel_launch(void* const* d_in, const int* in_sizes, int n_in,
                              void* d_out, int out_size, void* d_ws, size_t ws_size,
                              hipStream_t stream)
{
  const float* inSeq = (const float*)d_in[0];
  const int* targets = (const int*)d_in[1];
  const float* W1 = (const float*)d_in[2];
  const float* b1 = (const float*)d_in[3];
  const float* W2 = (const float*)d_in[4];
  const float* b2 = (const float*)d_in[5];
  const float* outW = (const float*)d_in[6];
  const float* outB = (const float*)d_in[7];
  float* out = (float*)d_out;

  // workspace layout: fallback-needed arrays first (~104 MB), then the
  // persistent-only extras (flags + h1 ring) -> ~112 MB total.
  char* w = (char*)d_ws;
  auto alloc = [&](size_t bytes) {
    char* r = w;
    w += (bytes + 255) & ~(size_t)255;
    return r;
  };
  unsigned short* W1p = (unsigned short*)alloc((size_t)4096 * K1_ * 2);
  unsigned short* W2p = (unsigned short*)alloc((size_t)4096 * K2_ * 2);
  unsigned short* xbf = (unsigned short*)alloc((size_t)T_ * B_ * D_ * 2);
  unsigned short* h1b = (unsigned short*)alloc((size_t)2 * B_ * H_ * 2);
  unsigned short* h2all = (unsigned short*)alloc((size_t)(T_ + 1) * B_ * H_ * 2);
  float* c1 = (float*)alloc((size_t)B_ * H_ * 4);
  float* c2 = (float*)alloc((size_t)B_ * H_ * 4);
  unsigned short* outWp = (unsigned short*)alloc((size_t)H_ * D_ * 2);
  float* loss = (float*)alloc(256);
  int* f1 = (int*)alloc(256 * 4);
  int* f2 = (int*)alloc(256 * 4);
  unsigned short* h1r = (unsigned short*)alloc((size_t)R_ * B_ * H_ * 2);

  const bool fits = ((size_t)(w - (char*)d_ws) <= ws_size);
  if (!fits) { f1 = nullptr; f2 = nullptr; h1r = nullptr; }

  prep_misc<<<dim3((T_ * B_ * D_) / 256), dim3(256), 0, stream>>>(
      inSeq, outW, xbf, outWp, h1b, h1r, h2all, c1, c2, loss, f1, f2);
  pack_w<<<dim3(K1_ / 64, 16, 4), dim3(256), 0, stream>>>(W1, W1p, K1_);
  pack_w<<<dim3(K2_ / 64, 16, 4), dim3(256), 0, stream>>>(W2, W2p, K2_);

  hipError_t ce = hipErrorUnknown;
  if (fits) {
    void* kargs[] = {(void*)&xbf, (void*)&W1p, (void*)&W2p, (void*)&b1,
                     (void*)&b2,  (void*)&h1r, (void*)&h2all,
                     (void*)&f1,  (void*)&f2};
    ce = hipLaunchCooperativeKernel((const void*)lstm_persistent,
                                    dim3(512), dim3(256), kargs, 0, stream);
  }
  if (ce != hipSuccess) {
    // Fallback: verified per-phase launch loop.
    (void)hipGetLastError();
    for (int p = 0; p <= T_; ++p)
      phase_kernel<<<dim3(512), dim3(256), 0, stream>>>(
          p, xbf, W1p, W2p, b1, b2, h1b, h2all, c1, c2);
  }

  proj_kernel<<<dim3(256), dim3(256), 0, stream>>>(
      h2all + (size_t)B_ * H_, outWp, outB, targets, out, loss);
  finalize_loss<<<dim3(1), dim3(1), 0, stream>>>(loss, out);
}